// Round 1
// baseline (798.585 us; speedup 1.0000x reference)
//
#include <hip/hip_runtime.h>
#include <hip/hip_bf16.h>

#define THR 0.1f
#define COS_EPS 1e-8f
#define LN_EPS 1e-5f

__device__ __forceinline__ float wave_sum(float v) {
    #pragma unroll
    for (int o = 1; o < 64; o <<= 1) v += __shfl_xor(v, o);
    return v;
}
__device__ __forceinline__ float wave_max(float v) {
    #pragma unroll
    for (int o = 1; o < 64; o <<= 1) v = fmaxf(v, __shfl_xor(v, o));
    return v;
}

// ---------------- CSR build ----------------
__global__ void count_k(const int* __restrict__ dst, int E, int* __restrict__ counts) {
    int e = blockIdx.x * 256 + threadIdx.x;
    if (e < E) atomicAdd(&counts[dst[e]], 1);
}

// single-block scan: counts[0..n-1] -> offs[0..n] (exclusive); counts becomes cursor copy
__global__ void scan_k(int* __restrict__ counts, int* __restrict__ offs, int n) {
    __shared__ int s[1024];
    int t = threadIdx.x;
    int chunk = (n + 1023) / 1024;
    int lo = t * chunk, hi = lo + chunk;
    if (lo > n) lo = n;
    if (hi > n) hi = n;
    int sum = 0;
    for (int i = lo; i < hi; ++i) sum += counts[i];
    s[t] = sum;
    __syncthreads();
    #pragma unroll
    for (int d = 1; d < 1024; d <<= 1) {
        int v = (t >= d) ? s[t - d] : 0;
        __syncthreads();
        s[t] += v;
        __syncthreads();
    }
    int run = s[t] - sum;  // exclusive base
    for (int i = lo; i < hi; ++i) {
        int c = counts[i];
        offs[i] = run;
        counts[i] = run;   // cursor
        run += c;
    }
    if (t == 1023) offs[n] = s[1023];
}

__global__ void scatter_k(const int* __restrict__ src, const int* __restrict__ dst, int E,
                          int* __restrict__ cursor, int* __restrict__ csr_src) {
    int e = blockIdx.x * 256 + threadIdx.x;
    if (e < E) {
        int p = atomicAdd(&cursor[dst[e]], 1);
        csr_src[p] = src[e];
    }
}

// ---------------- per-node normalize (f_in = 128) ----------------
__global__ void norm_k(const float* __restrict__ h, float* __restrict__ hn, int n) {
    int node = (blockIdx.x * blockDim.x + threadIdx.x) >> 6;
    int lane = threadIdx.x & 63;
    if (node >= n) return;
    float2 v = *(const float2*)(h + (size_t)node * 128 + lane * 2);
    float ss = wave_sum(v.x * v.x + v.y * v.y);
    float inv = 1.0f / fmaxf(sqrtf(ss), COS_EPS);
    float2 o;
    o.x = v.x * inv;
    o.y = v.y * inv;
    *(float2*)(hn + (size_t)node * 128 + lane * 2) = o;
}

// ---------------- GEMM: C[M][FOUT] = A[M][128] @ B[128][FOUT] ----------------
template <int FOUT>
__global__ void gemm_k(const float* __restrict__ A, const float* __restrict__ B,
                       float* __restrict__ C, int M) {
    constexpr int CG = FOUT / 8;    // col groups (16 or 8)
    constexpr int RG = 256 / CG;    // row groups (16 or 32)
    constexpr int RPT = 64 / RG;    // rows per thread (4 or 2)
    __shared__ float sA[64][33];
    __shared__ float sB[32][FOUT + 4];
    int row0 = blockIdx.x * 64;
    int tid = threadIdx.x;
    int tx = tid % CG, ty = tid / CG;
    float acc[RPT][8];
    #pragma unroll
    for (int r = 0; r < RPT; ++r)
        #pragma unroll
        for (int j = 0; j < 8; ++j) acc[r][j] = 0.f;

    for (int k0 = 0; k0 < 128; k0 += 32) {
        for (int i = tid; i < 64 * 32; i += 256) {
            int r = i >> 5, c = i & 31;
            sA[r][c] = (row0 + r < M) ? A[(size_t)(row0 + r) * 128 + k0 + c] : 0.f;
        }
        for (int i = tid; i < 32 * FOUT; i += 256) {
            int r = i / FOUT, c = i % FOUT;
            sB[r][c] = B[(size_t)(k0 + r) * FOUT + c];
        }
        __syncthreads();
        #pragma unroll
        for (int kk = 0; kk < 32; ++kk) {
            float b[8];
            #pragma unroll
            for (int j = 0; j < 8; ++j) b[j] = sB[kk][tx * 8 + j];
            #pragma unroll
            for (int r = 0; r < RPT; ++r) {
                float a = sA[ty * RPT + r][kk];
                #pragma unroll
                for (int j = 0; j < 8; ++j) acc[r][j] += a * b[j];
            }
        }
        __syncthreads();
    }
    #pragma unroll
    for (int r = 0; r < RPT; ++r) {
        int rr = row0 + ty * RPT + r;
        if (rr < M) {
            #pragma unroll
            for (int j = 0; j < 8; ++j) C[(size_t)rr * FOUT + tx * 8 + j] = acc[r][j];
        }
    }
}

// ---------------- aggregation: one wave per destination node ----------------
template <int FOUT>
__global__ void agg_k(const float* __restrict__ hn, const float* __restrict__ xl,
                      const int* __restrict__ offs, const int* __restrict__ csr,
                      const float* __restrict__ bias, float* __restrict__ out, int n) {
    int node = (blockIdx.x * blockDim.x + threadIdx.x) >> 6;
    int lane = threadIdx.x & 63;
    if (node >= n) return;
    const float2 hd = *(const float2*)(hn + (size_t)node * 128 + lane * 2);
    // self loop
    float p = wave_sum(hd.x * hd.x + hd.y * hd.y);
    float a = (p < THR) ? 1e-6f : p;
    float denom = a;
    float acc0, acc1 = 0.f;
    if constexpr (FOUT == 128) {
        float2 x0 = *(const float2*)(xl + (size_t)node * 128 + lane * 2);
        acc0 = a * x0.x;
        acc1 = a * x0.y;
    } else {
        acc0 = a * xl[(size_t)node * 64 + lane];
    }
    int b = offs[node], e = offs[node + 1];
    for (int i = b; i < e; ++i) {
        int s = csr[i];
        const float2 hs = *(const float2*)(hn + (size_t)s * 128 + lane * 2);
        float pe = wave_sum(hd.x * hs.x + hd.y * hs.y);
        float av = (pe < THR) ? 1e-6f : pe;
        denom += av;
        if constexpr (FOUT == 128) {
            float2 xs = *(const float2*)(xl + (size_t)s * 128 + lane * 2);
            acc0 += av * xs.x;
            acc1 += av * xs.y;
        } else {
            acc0 += av * xl[(size_t)s * 64 + lane];
        }
    }
    float inv = 1.0f / denom;
    if constexpr (FOUT == 128) {
        float2 o;
        o.x = acc0 * inv + bias[lane * 2];
        o.y = acc1 * inv + bias[lane * 2 + 1];
        *(float2*)(out + (size_t)node * 128 + lane * 2) = o;
    } else {
        out[(size_t)node * 64 + lane] = acc0 * inv + bias[lane];
    }
}

// ---------------- fused LayerNorm + ReLU (128 ch) ----------------
__global__ void ln_relu_k(const float* __restrict__ in, const float* __restrict__ g,
                          const float* __restrict__ be, float* __restrict__ outp, int n) {
    int node = (blockIdx.x * blockDim.x + threadIdx.x) >> 6;
    int lane = threadIdx.x & 63;
    if (node >= n) return;
    float2 v = *(const float2*)(in + (size_t)node * 128 + lane * 2);
    float m = wave_sum(v.x + v.y) * (1.0f / 128.f);
    float dx = v.x - m, dy = v.y - m;
    float var = wave_sum(dx * dx + dy * dy) * (1.0f / 128.f);
    float rs = rsqrtf(var + LN_EPS);
    float2 gg = *(const float2*)(g + lane * 2);
    float2 bb = *(const float2*)(be + lane * 2);
    float2 o;
    o.x = fmaxf(dx * rs * gg.x + bb.x, 0.f);
    o.y = fmaxf(dy * rs * gg.y + bb.y, 0.f);
    *(float2*)(outp + (size_t)node * 128 + lane * 2) = o;
}

// ---------------- log_softmax over 64 ----------------
__global__ void lsm_k(const float* __restrict__ in, float* __restrict__ outp, int n) {
    int node = (blockIdx.x * blockDim.x + threadIdx.x) >> 6;
    int lane = threadIdx.x & 63;
    if (node >= n) return;
    float v = in[(size_t)node * 64 + lane];
    float m = wave_max(v);
    float s = wave_sum(expf(v - m));
    outp[(size_t)node * 64 + lane] = v - m - logf(s);
}

extern "C" void kernel_launch(void* const* d_in, const int* in_sizes, int n_in,
                              void* d_out, int out_size, void* d_ws, size_t ws_size,
                              hipStream_t stream) {
    const float* x  = (const float*)d_in[0];
    const int* ei   = (const int*)d_in[1];
    const float* W0 = (const float*)d_in[2];
    const float* b0 = (const float*)d_in[3];
    const float* W1 = (const float*)d_in[4];
    const float* b1 = (const float*)d_in[5];
    const float* W2 = (const float*)d_in[6];
    const float* b2 = (const float*)d_in[7];
    const float* g1 = (const float*)d_in[8];
    const float* be1 = (const float*)d_in[9];
    const float* g2 = (const float*)d_in[10];
    const float* be2 = (const float*)d_in[11];

    const int N = in_sizes[0] / 128;
    const int E = in_sizes[1] / 2;
    const int* src = ei;
    const int* dst = ei + E;

    // workspace carve (256B aligned)
    size_t off = 0;
    auto carve = [&](size_t bytes) {
        void* p = (char*)d_ws + off;
        off += (bytes + 255) & ~(size_t)255;
        return p;
    };
    float* buf_h = (float*)carve((size_t)N * 128 * 4);
    float* hn    = (float*)carve((size_t)N * 128 * 4);
    float* xl    = (float*)carve((size_t)N * 128 * 4);
    int* counts  = (int*)carve((size_t)(N + 1) * 4);  // becomes cursor after scan
    int* offs    = (int*)carve((size_t)(N + 1) * 4);
    int* csr     = (int*)carve((size_t)E * 4);

    // CSR by destination
    hipMemsetAsync(counts, 0, (size_t)(N + 1) * 4, stream);
    count_k<<<(E + 255) / 256, 256, 0, stream>>>(dst, E, counts);
    scan_k<<<1, 1024, 0, stream>>>(counts, offs, N);
    scatter_k<<<(E + 255) / 256, 256, 0, stream>>>(src, dst, E, counts, csr);

    const int gridN4 = (N + 3) / 4;   // 4 waves/block, 1 node per wave
    const int gridG = (N + 63) / 64;  // gemm: 64 rows per block

    // ---- layer 0: x (f32[N,128]) -> buf_h
    norm_k<<<gridN4, 256, 0, stream>>>(x, hn, N);
    gemm_k<128><<<gridG, 256, 0, stream>>>(x, W0, xl, N);
    agg_k<128><<<gridN4, 256, 0, stream>>>(hn, xl, offs, csr, b0, buf_h, N);
    ln_relu_k<<<gridN4, 256, 0, stream>>>(buf_h, g1, be1, buf_h, N);

    // ---- layer 1: buf_h -> buf_h
    norm_k<<<gridN4, 256, 0, stream>>>(buf_h, hn, N);
    gemm_k<128><<<gridG, 256, 0, stream>>>(buf_h, W1, xl, N);
    agg_k<128><<<gridN4, 256, 0, stream>>>(hn, xl, offs, csr, b1, buf_h, N);
    ln_relu_k<<<gridN4, 256, 0, stream>>>(buf_h, g2, be2, buf_h, N);

    // ---- layer 2: buf_h -> d_out (64 ch + log_softmax)
    norm_k<<<gridN4, 256, 0, stream>>>(buf_h, hn, N);
    gemm_k<64><<<gridG, 256, 0, stream>>>(buf_h, W2, xl, N);
    agg_k<64><<<gridN4, 256, 0, stream>>>(hn, xl, offs, csr, b2, buf_h, N);
    lsm_k<<<gridN4, 256, 0, stream>>>(buf_h, (float*)d_out, N);
}

// Round 2
// 719.266 us; speedup vs baseline: 1.1103x; 1.1103x over previous
//
#include <hip/hip_runtime.h>
#include <hip/hip_bf16.h>

#define THR 0.1f
#define COS_EPS 1e-8f
#define LN_EPS 1e-5f

__device__ __forceinline__ float wave_sum(float v) {
    #pragma unroll
    for (int o = 1; o < 64; o <<= 1) v += __shfl_xor(v, o);
    return v;
}
__device__ __forceinline__ float wave_max(float v) {
    #pragma unroll
    for (int o = 1; o < 64; o <<= 1) v = fmaxf(v, __shfl_xor(v, o));
    return v;
}

// ---------------- CSR build ----------------
__global__ void count_k(const int* __restrict__ dst, int E, int* __restrict__ counts) {
    int e = blockIdx.x * 256 + threadIdx.x;
    if (e < E) atomicAdd(&counts[dst[e]], 1);
}

__global__ void scan_k(int* __restrict__ counts, int* __restrict__ offs, int n) {
    __shared__ int s[1024];
    int t = threadIdx.x;
    int chunk = (n + 1023) / 1024;
    int lo = t * chunk, hi = lo + chunk;
    if (lo > n) lo = n;
    if (hi > n) hi = n;
    int sum = 0;
    for (int i = lo; i < hi; ++i) sum += counts[i];
    s[t] = sum;
    __syncthreads();
    #pragma unroll
    for (int d = 1; d < 1024; d <<= 1) {
        int v = (t >= d) ? s[t - d] : 0;
        __syncthreads();
        s[t] += v;
        __syncthreads();
    }
    int run = s[t] - sum;
    for (int i = lo; i < hi; ++i) {
        int c = counts[i];
        offs[i] = run;
        counts[i] = run;   // cursor
        run += c;
    }
    if (t == 1023) offs[n] = s[1023];
}

__global__ void scatter_k(const int* __restrict__ src, const int* __restrict__ dst, int E,
                          int* __restrict__ cursor, int* __restrict__ csr_src) {
    int e = blockIdx.x * 256 + threadIdx.x;
    if (e < E) {
        int p = atomicAdd(&cursor[dst[e]], 1);
        csr_src[p] = src[e];
    }
}

// ---------------- norm -> packed .xy ----------------
// P[node*64+lane] = {hn0, hn1, (xl0), (xl1)}  (xl written by gemm)
__global__ void normpack_k(const float* __restrict__ h, float4* __restrict__ P, int n) {
    int node = (blockIdx.x * blockDim.x + threadIdx.x) >> 6;
    int lane = threadIdx.x & 63;
    if (node >= n) return;
    float2 v = *(const float2*)(h + (size_t)node * 128 + lane * 2);
    float ss = wave_sum(v.x * v.x + v.y * v.y);
    float inv = 1.0f / fmaxf(sqrtf(ss), COS_EPS);
    float2 o = {v.x * inv, v.y * inv};
    *(float2*)&P[(size_t)node * 64 + lane].x = o;
}

// plain norm to dense hn [N][128] (layer 2)
__global__ void norm_k(const float* __restrict__ h, float* __restrict__ hn, int n) {
    int node = (blockIdx.x * blockDim.x + threadIdx.x) >> 6;
    int lane = threadIdx.x & 63;
    if (node >= n) return;
    float2 v = *(const float2*)(h + (size_t)node * 128 + lane * 2);
    float ss = wave_sum(v.x * v.x + v.y * v.y);
    float inv = 1.0f / fmaxf(sqrtf(ss), COS_EPS);
    float2 o = {v.x * inv, v.y * inv};
    *(float2*)(hn + (size_t)node * 128 + lane * 2) = o;
}

// ---------------- GEMM: [M][128] @ [128][FOUT] ----------------
// STRIDED: store feature col c into P[row*64 + c/2].{z,w}
template <int FOUT, bool STRIDED>
__global__ void gemm_k(const float* __restrict__ A, const float* __restrict__ B,
                       float* __restrict__ C, float4* __restrict__ P, int M) {
    constexpr int CG = FOUT / 8;
    constexpr int RG = 256 / CG;
    constexpr int RPT = 64 / RG;
    __shared__ float sA[64][33];
    __shared__ float sB[32][FOUT + 4];
    int row0 = blockIdx.x * 64;
    int tid = threadIdx.x;
    int tx = tid % CG, ty = tid / CG;
    float acc[RPT][8];
    #pragma unroll
    for (int r = 0; r < RPT; ++r)
        #pragma unroll
        for (int j = 0; j < 8; ++j) acc[r][j] = 0.f;

    for (int k0 = 0; k0 < 128; k0 += 32) {
        for (int i = tid; i < 64 * 32; i += 256) {
            int r = i >> 5, c = i & 31;
            sA[r][c] = (row0 + r < M) ? A[(size_t)(row0 + r) * 128 + k0 + c] : 0.f;
        }
        for (int i = tid; i < 32 * FOUT; i += 256) {
            int r = i / FOUT, c = i % FOUT;
            sB[r][c] = B[(size_t)(k0 + r) * FOUT + c];
        }
        __syncthreads();
        #pragma unroll
        for (int kk = 0; kk < 32; ++kk) {
            float b[8];
            #pragma unroll
            for (int j = 0; j < 8; ++j) b[j] = sB[kk][tx * 8 + j];
            #pragma unroll
            for (int r = 0; r < RPT; ++r) {
                float a = sA[ty * RPT + r][kk];
                #pragma unroll
                for (int j = 0; j < 8; ++j) acc[r][j] += a * b[j];
            }
        }
        __syncthreads();
    }
    #pragma unroll
    for (int r = 0; r < RPT; ++r) {
        int rr = row0 + ty * RPT + r;
        if (rr < M) {
            if constexpr (STRIDED) {
                #pragma unroll
                for (int jj = 0; jj < 4; ++jj) {
                    float2 v = {acc[r][2 * jj], acc[r][2 * jj + 1]};
                    *(float2*)&P[(size_t)rr * 64 + tx * 4 + jj].z = v;
                }
            } else {
                #pragma unroll
                for (int j = 0; j < 8; ++j) C[(size_t)rr * FOUT + tx * 8 + j] = acc[r][j];
            }
        }
    }
}

// ---------------- agg (128-wide) + fused LN+ReLU ----------------
// COND: skip xl load for below-threshold edges (drops 1e-6 msgs, err ~4e-6)
template <bool COND>
__global__ void agg128_k(const float4* __restrict__ P, const int* __restrict__ offs,
                         const int* __restrict__ csr, const float* __restrict__ bias,
                         const float* __restrict__ g, const float* __restrict__ be,
                         float* __restrict__ hout, int n) {
    int node = (blockIdx.x * blockDim.x + threadIdx.x) >> 6;
    int lane = threadIdx.x & 63;
    if (node >= n) return;
    float4 mine = P[(size_t)node * 64 + lane];
    float2 hd = {mine.x, mine.y};
    float p = wave_sum(hd.x * hd.x + hd.y * hd.y);
    float a = (p < THR) ? 1e-6f : p;
    float denom = a;
    float acc0 = a * mine.z, acc1 = a * mine.w;
    int b = offs[node], e = offs[node + 1];
    for (int i0 = b; i0 < e; i0 += 64) {
        int rem = e - i0;
        int cnt = rem < 64 ? rem : 64;
        int sidx = csr[i0 + (lane < rem ? lane : 0)];
        int s = __shfl(sidx, 0);
        const float4* curp = P + (size_t)s * 64 + lane;
        if constexpr (COND) {
            float2 hs_n = *(const float2*)curp;
            for (int j = 0; j < cnt; ++j) {
                float2 hs = hs_n;
                const float4* myp = curp;
                if (j + 1 < cnt) {
                    int s2 = __shfl(sidx, j + 1);
                    curp = P + (size_t)s2 * 64 + lane;
                    hs_n = *(const float2*)curp;
                }
                float pe = wave_sum(hd.x * hs.x + hd.y * hs.y);
                if (pe >= THR) {
                    float2 xs = *(const float2*)((const float*)myp + 2);
                    acc0 += pe * xs.x;
                    acc1 += pe * xs.y;
                    denom += pe;
                } else {
                    denom += 1e-6f;
                }
            }
        } else {
            float4 nxt = *curp;
            for (int j = 0; j < cnt; ++j) {
                float4 cur = nxt;
                if (j + 1 < cnt) {
                    int s2 = __shfl(sidx, j + 1);
                    nxt = P[(size_t)s2 * 64 + lane];
                }
                float pe = wave_sum(hd.x * cur.x + hd.y * cur.y);
                float av = (pe < THR) ? 1e-6f : pe;
                denom += av;
                acc0 += av * cur.z;
                acc1 += av * cur.w;
            }
        }
    }
    float inv = 1.0f / denom;
    float ox = acc0 * inv + bias[lane * 2];
    float oy = acc1 * inv + bias[lane * 2 + 1];
    float m = wave_sum(ox + oy) * (1.0f / 128.f);
    float dx = ox - m, dy = oy - m;
    float var = wave_sum(dx * dx + dy * dy) * (1.0f / 128.f);
    float rs = rsqrtf(var + LN_EPS);
    float2 gg = *(const float2*)(g + lane * 2);
    float2 bb = *(const float2*)(be + lane * 2);
    float2 o;
    o.x = fmaxf(dx * rs * gg.x + bb.x, 0.f);
    o.y = fmaxf(dy * rs * gg.y + bb.y, 0.f);
    *(float2*)(hout + (size_t)node * 128 + lane * 2) = o;
}

// ---------------- agg (64-wide) + fused log_softmax ----------------
__global__ void agg64_k(const float* __restrict__ hn, const float* __restrict__ xl,
                        const int* __restrict__ offs, const int* __restrict__ csr,
                        const float* __restrict__ bias, float* __restrict__ out, int n) {
    int node = (blockIdx.x * blockDim.x + threadIdx.x) >> 6;
    int lane = threadIdx.x & 63;
    if (node >= n) return;
    float2 hd = *(const float2*)(hn + (size_t)node * 128 + lane * 2);
    float x0 = xl[(size_t)node * 64 + lane];
    float p = wave_sum(hd.x * hd.x + hd.y * hd.y);
    float a = (p < THR) ? 1e-6f : p;
    float denom = a;
    float acc = a * x0;
    int b = offs[node], e = offs[node + 1];
    for (int i0 = b; i0 < e; i0 += 64) {
        int rem = e - i0;
        int cnt = rem < 64 ? rem : 64;
        int sidx = csr[i0 + (lane < rem ? lane : 0)];
        int s = __shfl(sidx, 0);
        float2 hs_n = *(const float2*)(hn + (size_t)s * 128 + lane * 2);
        float xs_n = xl[(size_t)s * 64 + lane];
        for (int j = 0; j < cnt; ++j) {
            float2 hs = hs_n;
            float xs = xs_n;
            if (j + 1 < cnt) {
                int s2 = __shfl(sidx, j + 1);
                hs_n = *(const float2*)(hn + (size_t)s2 * 128 + lane * 2);
                xs_n = xl[(size_t)s2 * 64 + lane];
            }
            float pe = wave_sum(hd.x * hs.x + hd.y * hs.y);
            float av = (pe < THR) ? 1e-6f : pe;
            denom += av;
            acc += av * xs;
        }
    }
    float v = acc / denom + bias[lane];
    float m = wave_max(v);
    float s = wave_sum(expf(v - m));
    out[(size_t)node * 64 + lane] = v - m - logf(s);
}

extern "C" void kernel_launch(void* const* d_in, const int* in_sizes, int n_in,
                              void* d_out, int out_size, void* d_ws, size_t ws_size,
                              hipStream_t stream) {
    const float* x  = (const float*)d_in[0];
    const int* ei   = (const int*)d_in[1];
    const float* W0 = (const float*)d_in[2];
    const float* b0 = (const float*)d_in[3];
    const float* W1 = (const float*)d_in[4];
    const float* b1 = (const float*)d_in[5];
    const float* W2 = (const float*)d_in[6];
    const float* b2 = (const float*)d_in[7];
    const float* g1 = (const float*)d_in[8];
    const float* be1 = (const float*)d_in[9];
    const float* g2 = (const float*)d_in[10];
    const float* be2 = (const float*)d_in[11];

    const int N = in_sizes[0] / 128;
    const int E = in_sizes[1] / 2;
    const int* src = ei;
    const int* dst = ei + E;

    size_t off = 0;
    auto carve = [&](size_t bytes) {
        void* p = (char*)d_ws + off;
        off += (bytes + 255) & ~(size_t)255;
        return p;
    };
    float*  h      = (float*)carve((size_t)N * 128 * 4);   // 25.6 MB
    float4* P      = (float4*)carve((size_t)N * 64 * 16);  // 51.2 MB
    int* counts    = (int*)carve((size_t)(N + 1) * 4);
    int* offs      = (int*)carve((size_t)(N + 1) * 4);
    int* csr       = (int*)carve((size_t)E * 4);
    // layer-2 reuse of P's space:
    float* hn   = (float*)P;                                // 25.6 MB
    float* xl64 = (float*)((char*)P + (size_t)N * 128 * 4); // 12.8 MB

    // CSR by destination
    hipMemsetAsync(counts, 0, (size_t)(N + 1) * 4, stream);
    count_k<<<(E + 255) / 256, 256, 0, stream>>>(dst, E, counts);
    scan_k<<<1, 1024, 0, stream>>>(counts, offs, N);
    scatter_k<<<(E + 255) / 256, 256, 0, stream>>>(src, dst, E, counts, csr);

    const int gridN4 = (N + 3) / 4;
    const int gridG = (N + 63) / 64;

    // ---- layer 0: x -> h
    gemm_k<128, true><<<gridG, 256, 0, stream>>>(x, W0, nullptr, P, N);
    normpack_k<<<gridN4, 256, 0, stream>>>(x, P, N);
    agg128_k<true><<<gridN4, 256, 0, stream>>>(P, offs, csr, b0, g1, be1, h, N);

    // ---- layer 1: h -> h
    gemm_k<128, true><<<gridG, 256, 0, stream>>>(h, W1, nullptr, P, N);
    normpack_k<<<gridN4, 256, 0, stream>>>(h, P, N);
    agg128_k<false><<<gridN4, 256, 0, stream>>>(P, offs, csr, b1, g2, be2, h, N);

    // ---- layer 2: h -> d_out
    gemm_k<64, false><<<gridG, 256, 0, stream>>>(h, W2, xl64, nullptr, N);
    norm_k<<<gridN4, 256, 0, stream>>>(h, hn, N);
    agg64_k<<<gridN4, 256, 0, stream>>>(hn, xl64, offs, csr, b2, (float*)d_out, N);
}

// Round 3
// 544.477 us; speedup vs baseline: 1.4667x; 1.3210x over previous
//
#include <hip/hip_runtime.h>
#include <hip/hip_bf16.h>

#define THR 0.1f
#define COS_EPS 1e-8f
#define LN_EPS 1e-5f

__device__ __forceinline__ float wave_sum(float v) {
    #pragma unroll
    for (int o = 1; o < 64; o <<= 1) v += __shfl_xor(v, o);
    return v;
}
__device__ __forceinline__ float gsum16(float v) {
    #pragma unroll
    for (int o = 1; o < 16; o <<= 1) v += __shfl_xor(v, o);
    return v;
}
__device__ __forceinline__ float gsum8(float v) {
    #pragma unroll
    for (int o = 1; o < 8; o <<= 1) v += __shfl_xor(v, o);
    return v;
}
__device__ __forceinline__ float gmax8(float v) {
    #pragma unroll
    for (int o = 1; o < 8; o <<= 1) v = fmaxf(v, __shfl_xor(v, o));
    return v;
}

// ---------------- CSR build ----------------
__global__ void count_k(const int* __restrict__ dst, int E, int* __restrict__ counts) {
    int e = blockIdx.x * 256 + threadIdx.x;
    if (e < E) atomicAdd(&counts[dst[e]], 1);
}

__global__ void scan_k(int* __restrict__ counts, int* __restrict__ offs, int n) {
    __shared__ int s[1024];
    int t = threadIdx.x;
    int chunk = (n + 1023) / 1024;
    int lo = t * chunk, hi = lo + chunk;
    if (lo > n) lo = n;
    if (hi > n) hi = n;
    int sum = 0;
    for (int i = lo; i < hi; ++i) sum += counts[i];
    s[t] = sum;
    __syncthreads();
    #pragma unroll
    for (int d = 1; d < 1024; d <<= 1) {
        int v = (t >= d) ? s[t - d] : 0;
        __syncthreads();
        s[t] += v;
        __syncthreads();
    }
    int run = s[t] - sum;
    for (int i = lo; i < hi; ++i) {
        int c = counts[i];
        offs[i] = run;
        counts[i] = run;   // cursor
        run += c;
    }
    if (t == 1023) offs[n] = s[1023];
}

__global__ void scatter_k(const int* __restrict__ src, const int* __restrict__ dst, int E,
                          int* __restrict__ cursor, int* __restrict__ csr_src) {
    int e = blockIdx.x * 256 + threadIdx.x;
    if (e < E) {
        int p = atomicAdd(&cursor[dst[e]], 1);
        csr_src[p] = src[e];
    }
}

// ---------------- normalize x -> hn + norms ----------------
__global__ void normpack_k(const float* __restrict__ h, float* __restrict__ hn,
                           float* __restrict__ norms, int n) {
    int node = (blockIdx.x * blockDim.x + threadIdx.x) >> 6;
    int lane = threadIdx.x & 63;
    if (node >= n) return;
    float2 v = *(const float2*)(h + (size_t)node * 128 + lane * 2);
    float ss = wave_sum(v.x * v.x + v.y * v.y);
    float nrm = sqrtf(ss);
    float inv = 1.0f / fmaxf(nrm, COS_EPS);
    float2 o = {v.x * inv, v.y * inv};
    *(float2*)(hn + (size_t)node * 128 + lane * 2) = o;
    if (lane == 0) norms[node] = nrm;
}

// ---------------- aggregation on RAW features via hn*norm ----------------
// r[node] = (a_self*nd*hn_d + sum_e a_e*norm_s*hn_s) / denom
__global__ void agg_k(const float* __restrict__ hn, const float* __restrict__ norms,
                      const int* __restrict__ offs, const int* __restrict__ csr,
                      float* __restrict__ r, int n) {
    int node = (blockIdx.x * blockDim.x + threadIdx.x) >> 6;
    int lane = threadIdx.x & 63;
    if (node >= n) return;
    const float2 hd = *(const float2*)(hn + (size_t)node * 128 + lane * 2);
    float p = wave_sum(hd.x * hd.x + hd.y * hd.y);
    float a = (p < THR) ? 1e-6f : p;
    float nd = norms[node];
    float denom = a;
    float w = a * nd;
    float acc0 = w * hd.x, acc1 = w * hd.y;
    int b = offs[node], e = offs[node + 1];
    for (int i0 = b; i0 < e; i0 += 64) {
        int rem = e - i0;
        int cnt = rem < 64 ? rem : 64;
        int sidx = csr[i0 + (lane < rem ? lane : 0)];
        int s0 = __shfl(sidx, 0);
        float2 h0 = *(const float2*)(hn + (size_t)s0 * 128 + lane * 2);
        float n0 = norms[s0];
        float2 h1 = h0;
        float n1 = 0.f;
        if (cnt > 1) {
            int s1 = __shfl(sidx, 1);
            h1 = *(const float2*)(hn + (size_t)s1 * 128 + lane * 2);
            n1 = norms[s1];
        }
        for (int j = 0; j < cnt; j += 2) {
            float2 c0 = h0, c1 = h1;
            float m0 = n0, m1 = n1;
            bool has1 = (j + 1) < cnt;
            if (j + 2 < cnt) {
                int s = __shfl(sidx, j + 2);
                h0 = *(const float2*)(hn + (size_t)s * 128 + lane * 2);
                n0 = norms[s];
            }
            if (j + 3 < cnt) {
                int s = __shfl(sidx, j + 3);
                h1 = *(const float2*)(hn + (size_t)s * 128 + lane * 2);
                n1 = norms[s];
            }
            float t0 = hd.x * c0.x + hd.y * c0.y;
            float t1 = hd.x * c1.x + hd.y * c1.y;
            #pragma unroll
            for (int o = 1; o < 64; o <<= 1) {   // two interleaved butterflies
                t0 += __shfl_xor(t0, o);
                t1 += __shfl_xor(t1, o);
            }
            float av0 = (t0 < THR) ? 1e-6f : t0;
            denom += av0;
            float w0 = av0 * m0;
            acc0 += w0 * c0.x;
            acc1 += w0 * c0.y;
            if (has1) {
                float av1 = (t1 < THR) ? 1e-6f : t1;
                denom += av1;
                float w1 = av1 * m1;
                acc0 += w1 * c1.x;
                acc1 += w1 * c1.y;
            }
        }
    }
    float inv = 1.0f / denom;
    float2 o = {acc0 * inv, acc1 * inv};
    *(float2*)(r + (size_t)node * 128 + lane * 2) = o;
}

// ---------------- GEMM [M][128]@[128][128] + bias + LN + ReLU + re-normalize ----------------
// In-place safe: each block reads only its own 64 rows of A before storing them.
__global__ void gemm_ln_k(const float* __restrict__ A, const float* __restrict__ B,
                          const float* __restrict__ bias, const float* __restrict__ g,
                          const float* __restrict__ be, float* __restrict__ hn,
                          float* __restrict__ norms, int M) {
    __shared__ float sA[64][33];
    __shared__ float sB[32][132];
    int row0 = blockIdx.x * 64;
    int tid = threadIdx.x;
    int tx = tid & 15, ty = tid >> 4;
    float acc[4][8];
    #pragma unroll
    for (int r = 0; r < 4; ++r)
        #pragma unroll
        for (int j = 0; j < 8; ++j) acc[r][j] = 0.f;

    for (int k0 = 0; k0 < 128; k0 += 32) {
        for (int i = tid; i < 64 * 32; i += 256) {
            int r = i >> 5, c = i & 31;
            sA[r][c] = (row0 + r < M) ? A[(size_t)(row0 + r) * 128 + k0 + c] : 0.f;
        }
        for (int i = tid; i < 32 * 128; i += 256) {
            int r = i >> 7, c = i & 127;
            sB[r][c] = B[(size_t)(k0 + r) * 128 + c];
        }
        __syncthreads();
        #pragma unroll
        for (int kk = 0; kk < 32; ++kk) {
            float bb[8];
            #pragma unroll
            for (int j = 0; j < 8; ++j) bb[j] = sB[kk][tx * 8 + j];
            #pragma unroll
            for (int r = 0; r < 4; ++r) {
                float a = sA[ty * 4 + r][kk];
                #pragma unroll
                for (int j = 0; j < 8; ++j) acc[r][j] += a * bb[j];
            }
        }
        __syncthreads();
    }
    float4 b4a = *(const float4*)(bias + tx * 8);
    float4 b4b = *(const float4*)(bias + tx * 8 + 4);
    float4 g4a = *(const float4*)(g + tx * 8);
    float4 g4b = *(const float4*)(g + tx * 8 + 4);
    float4 e4a = *(const float4*)(be + tx * 8);
    float4 e4b = *(const float4*)(be + tx * 8 + 4);
    const float* bp = &b4a.x;
    const float* gp = &g4a.x;
    const float* ep = &e4a.x;
    #pragma unroll
    for (int r = 0; r < 4; ++r) {
        int row = row0 + ty * 4 + r;
        float o[8];
        float ls = 0.f;
        #pragma unroll
        for (int j = 0; j < 8; ++j) {
            o[j] = acc[r][j] + (j < 4 ? (&b4a.x)[j] : (&b4b.x)[j - 4]);
            ls += o[j];
        }
        float m = gsum16(ls) * (1.0f / 128.f);
        float vv = 0.f;
        float d[8];
        #pragma unroll
        for (int j = 0; j < 8; ++j) {
            d[j] = o[j] - m;
            vv += d[j] * d[j];
        }
        float var = gsum16(vv) * (1.0f / 128.f);
        float rs = rsqrtf(var + LN_EPS);
        float y[8];
        float ss = 0.f;
        #pragma unroll
        for (int j = 0; j < 8; ++j) {
            float gj = (j < 4 ? (&g4a.x)[j] : (&g4b.x)[j - 4]);
            float ej = (j < 4 ? (&e4a.x)[j] : (&e4b.x)[j - 4]);
            y[j] = fmaxf(d[j] * rs * gj + ej, 0.f);
            ss += y[j] * y[j];
        }
        float sst = gsum16(ss);
        float nrm = sqrtf(sst);
        float inv = 1.0f / fmaxf(nrm, COS_EPS);
        if (row < M) {
            float4 o0 = {y[0] * inv, y[1] * inv, y[2] * inv, y[3] * inv};
            float4 o1 = {y[4] * inv, y[5] * inv, y[6] * inv, y[7] * inv};
            *(float4*)(hn + (size_t)row * 128 + tx * 8) = o0;
            *(float4*)(hn + (size_t)row * 128 + tx * 8 + 4) = o1;
            if (tx == 0) norms[row] = nrm;
        }
    }
    (void)bp; (void)gp; (void)ep;
}

// ---------------- GEMM [M][128]@[128][64] + bias + log_softmax -> out ----------------
__global__ void gemm_lsm_k(const float* __restrict__ A, const float* __restrict__ B,
                           const float* __restrict__ bias, float* __restrict__ out, int M) {
    __shared__ float sA[64][33];
    __shared__ float sB[32][68];
    int row0 = blockIdx.x * 64;
    int tid = threadIdx.x;
    int tx = tid & 7, ty = tid >> 3;
    float acc[2][8];
    #pragma unroll
    for (int r = 0; r < 2; ++r)
        #pragma unroll
        for (int j = 0; j < 8; ++j) acc[r][j] = 0.f;

    for (int k0 = 0; k0 < 128; k0 += 32) {
        for (int i = tid; i < 64 * 32; i += 256) {
            int r = i >> 5, c = i & 31;
            sA[r][c] = (row0 + r < M) ? A[(size_t)(row0 + r) * 128 + k0 + c] : 0.f;
        }
        for (int i = tid; i < 32 * 64; i += 256) {
            int r = i >> 6, c = i & 63;
            sB[r][c] = B[(size_t)(k0 + r) * 64 + c];
        }
        __syncthreads();
        #pragma unroll
        for (int kk = 0; kk < 32; ++kk) {
            float bb[8];
            #pragma unroll
            for (int j = 0; j < 8; ++j) bb[j] = sB[kk][tx * 8 + j];
            #pragma unroll
            for (int r = 0; r < 2; ++r) {
                float a = sA[ty * 2 + r][kk];
                #pragma unroll
                for (int j = 0; j < 8; ++j) acc[r][j] += a * bb[j];
            }
        }
        __syncthreads();
    }
    float4 b4a = *(const float4*)(bias + tx * 8);
    float4 b4b = *(const float4*)(bias + tx * 8 + 4);
    #pragma unroll
    for (int r = 0; r < 2; ++r) {
        int row = row0 + ty * 2 + r;
        float v[8];
        float mx = -1e30f;
        #pragma unroll
        for (int j = 0; j < 8; ++j) {
            v[j] = acc[r][j] + (j < 4 ? (&b4a.x)[j] : (&b4b.x)[j - 4]);
            mx = fmaxf(mx, v[j]);
        }
        float m = gmax8(mx);
        float es = 0.f;
        #pragma unroll
        for (int j = 0; j < 8; ++j) es += __expf(v[j] - m);
        float s = gsum8(es);
        float ls = logf(s);
        if (row < M) {
            float4 o0 = {v[0] - m - ls, v[1] - m - ls, v[2] - m - ls, v[3] - m - ls};
            float4 o1 = {v[4] - m - ls, v[5] - m - ls, v[6] - m - ls, v[7] - m - ls};
            *(float4*)(out + (size_t)row * 64 + tx * 8) = o0;
            *(float4*)(out + (size_t)row * 64 + tx * 8 + 4) = o1;
        }
    }
}

extern "C" void kernel_launch(void* const* d_in, const int* in_sizes, int n_in,
                              void* d_out, int out_size, void* d_ws, size_t ws_size,
                              hipStream_t stream) {
    const float* x  = (const float*)d_in[0];
    const int* ei   = (const int*)d_in[1];
    const float* W0 = (const float*)d_in[2];
    const float* b0 = (const float*)d_in[3];
    const float* W1 = (const float*)d_in[4];
    const float* b1 = (const float*)d_in[5];
    const float* W2 = (const float*)d_in[6];
    const float* b2 = (const float*)d_in[7];
    const float* g1 = (const float*)d_in[8];
    const float* be1 = (const float*)d_in[9];
    const float* g2 = (const float*)d_in[10];
    const float* be2 = (const float*)d_in[11];

    const int N = in_sizes[0] / 128;
    const int E = in_sizes[1] / 2;
    const int* src = ei;
    const int* dst = ei + E;

    size_t off = 0;
    auto carve = [&](size_t bytes) {
        void* p = (char*)d_ws + off;
        off += (bytes + 255) & ~(size_t)255;
        return p;
    };
    float* bufA  = (float*)carve((size_t)N * 128 * 4);
    float* bufB  = (float*)carve((size_t)N * 128 * 4);
    float* nA    = (float*)carve((size_t)N * 4);
    float* nB    = (float*)carve((size_t)N * 4);
    int* counts  = (int*)carve((size_t)(N + 1) * 4);
    int* offs    = (int*)carve((size_t)(N + 1) * 4);
    int* csr     = (int*)carve((size_t)E * 4);

    // CSR by destination
    hipMemsetAsync(counts, 0, (size_t)(N + 1) * 4, stream);
    count_k<<<(E + 255) / 256, 256, 0, stream>>>(dst, E, counts);
    scan_k<<<1, 1024, 0, stream>>>(counts, offs, N);
    scatter_k<<<(E + 255) / 256, 256, 0, stream>>>(src, dst, E, counts, csr);

    const int gridN4 = (N + 3) / 4;
    const int gridG = (N + 63) / 64;

    // ---- layer 0
    normpack_k<<<gridN4, 256, 0, stream>>>(x, bufA, nA, N);
    agg_k<<<gridN4, 256, 0, stream>>>(bufA, nA, offs, csr, bufB, N);
    gemm_ln_k<<<gridG, 256, 0, stream>>>(bufB, W0, b0, g1, be1, bufB, nB, N);

    // ---- layer 1
    agg_k<<<gridN4, 256, 0, stream>>>(bufB, nB, offs, csr, bufA, N);
    gemm_ln_k<<<gridG, 256, 0, stream>>>(bufA, W1, b1, g2, be2, bufA, nA, N);

    // ---- layer 2
    agg_k<<<gridN4, 256, 0, stream>>>(bufA, nA, offs, csr, bufB, N);
    gemm_lsm_k<<<gridG, 256, 0, stream>>>(bufB, W2, b2, (float*)d_out, N);
}

// Round 4
// 418.000 us; speedup vs baseline: 1.9105x; 1.3026x over previous
//
#include <hip/hip_runtime.h>
#include <hip/hip_bf16.h>

#define THR 0.1f
#define COS_EPS 1e-8f
#define LN_EPS 1e-5f

__device__ __forceinline__ float wave_sum(float v) {
    #pragma unroll
    for (int o = 1; o < 64; o <<= 1) v += __shfl_xor(v, o);
    return v;
}
__device__ __forceinline__ float gsum16(float v) {
    #pragma unroll
    for (int o = 1; o < 16; o <<= 1) v += __shfl_xor(v, o);
    return v;
}
__device__ __forceinline__ float gsum8(float v) {
    #pragma unroll
    for (int o = 1; o < 8; o <<= 1) v += __shfl_xor(v, o);
    return v;
}
__device__ __forceinline__ float gmax8(float v) {
    #pragma unroll
    for (int o = 1; o < 8; o <<= 1) v = fmaxf(v, __shfl_xor(v, o));
    return v;
}

// ---------------- CSR build ----------------
__global__ void count_k(const int* __restrict__ dst, int E, int* __restrict__ counts) {
    int e = blockIdx.x * 256 + threadIdx.x;
    if (e < E) atomicAdd(&counts[dst[e]], 1);
}

// phase 1: per-1024-chunk sums
__global__ void scan1_k(const int* __restrict__ counts, int* __restrict__ partials, int ntot) {
    int base = blockIdx.x * 1024;
    int t = threadIdx.x;
    int s = 0;
    #pragma unroll
    for (int i = 0; i < 4; ++i) {
        int idx = base + t + i * 256;
        if (idx < ntot) s += counts[idx];
    }
    s = (int)wave_sum((float)s);  // exact for counts << 2^24
    __shared__ int ws[4];
    if ((t & 63) == 0) ws[t >> 6] = s;
    __syncthreads();
    if (t == 0) partials[blockIdx.x] = ws[0] + ws[1] + ws[2] + ws[3];
}

// phase 2: exclusive scan of <=64 partials, single wave
__global__ void scan2_k(int* __restrict__ partials, int nb) {
    int t = threadIdx.x;
    int v = (t < nb) ? partials[t] : 0;
    int orig = v;
    #pragma unroll
    for (int o = 1; o < 64; o <<= 1) {
        int u = __shfl_up(v, o);
        if (t >= o) v += u;
    }
    if (t < nb) partials[t] = v - orig;
}

// phase 3: local scan + add block offset; write offs and cursor (in-place over counts)
__global__ void scan3_k(int* __restrict__ counts, const int* __restrict__ partials,
                        int* __restrict__ offs, int ntot) {
    int base = blockIdx.x * 1024;
    int t = threadIdx.x;
    int lane = t & 63, wid = t >> 6;
    int idx = base + t * 4;
    int c[4];
    #pragma unroll
    for (int k = 0; k < 4; ++k) c[k] = (idx + k < ntot) ? counts[idx + k] : 0;
    int s = c[0] + c[1] + c[2] + c[3];
    int sc = s;
    #pragma unroll
    for (int o = 1; o < 64; o <<= 1) {
        int u = __shfl_up(sc, o);
        if (lane >= o) sc += u;
    }
    __shared__ int wsum[4];
    if (lane == 63) wsum[wid] = sc;
    __syncthreads();
    int add = partials[blockIdx.x];
    for (int w = 0; w < wid; ++w) add += wsum[w];
    int ex = add + sc - s;
    #pragma unroll
    for (int k = 0; k < 4; ++k) {
        if (idx + k < ntot) {
            offs[idx + k] = ex;
            counts[idx + k] = ex;  // cursor
            ex += c[k];
        }
    }
}

__global__ void scatter_k(const int* __restrict__ src, const int* __restrict__ dst, int E,
                          int* __restrict__ cursor, int* __restrict__ csr_src) {
    int e = blockIdx.x * 256 + threadIdx.x;
    if (e < E) {
        int p = atomicAdd(&cursor[dst[e]], 1);
        csr_src[p] = src[e];
    }
}

// ---------------- normalize x -> hn + norms ----------------
__global__ void normpack_k(const float* __restrict__ h, float* __restrict__ hn,
                           float* __restrict__ norms, int n) {
    int node = (blockIdx.x * blockDim.x + threadIdx.x) >> 6;
    int lane = threadIdx.x & 63;
    if (node >= n) return;
    float2 v = *(const float2*)(h + (size_t)node * 128 + lane * 2);
    float ss = wave_sum(v.x * v.x + v.y * v.y);
    float nrm = sqrtf(ss);
    float inv = 1.0f / fmaxf(nrm, COS_EPS);
    float2 o = {v.x * inv, v.y * inv};
    *(float2*)(hn + (size_t)node * 128 + lane * 2) = o;
    if (lane == 0) norms[node] = nrm;
}

// ---------------- aggregation: 4 lane-groups x 16 lanes, 1 edge/group/iter ----------------
// r[node] = (a_self*nd*hn_d + sum_e a_e*norm_s*hn_s) / denom
__global__ void agg_k(const float* __restrict__ hn, const float* __restrict__ norms,
                      const int* __restrict__ offs, const int* __restrict__ csr,
                      float* __restrict__ r, int n) {
    int node = (blockIdx.x * blockDim.x + threadIdx.x) >> 6;
    int lane = threadIdx.x & 63;
    if (node >= n) return;
    int g = lane >> 4;
    int q = lane & 15;
    const float* myrow = hn + (size_t)node * 128 + q * 8;
    float4 d0 = *(const float4*)myrow;
    float4 d1 = *(const float4*)(myrow + 4);
    float nd = norms[node];
    float p = d0.x * d0.x + d0.y * d0.y + d0.z * d0.z + d0.w * d0.w
            + d1.x * d1.x + d1.y * d1.y + d1.z * d1.z + d1.w * d1.w;
    p = gsum16(p);
    float4 a0 = {0.f, 0.f, 0.f, 0.f}, a1 = {0.f, 0.f, 0.f, 0.f};
    float denom = 0.f;
    int b = offs[node], e = offs[node + 1];
    for (int i0 = b; i0 < e; i0 += 64) {
        int cnt = e - i0;
        if (cnt > 64) cnt = 64;
        int sidx = csr[i0 + (lane < cnt ? lane : 0)];
        int jp = (g < cnt) ? g : 0;
        int s = __shfl(sidx, jp);
        const float* sp = hn + (size_t)s * 128 + q * 8;
        float4 h0 = *(const float4*)sp;
        float4 h1 = *(const float4*)(sp + 4);
        float ns = norms[s];
        for (int j = 0; j < cnt; j += 4) {
            float4 c0 = h0, c1 = h1;
            float cn = ns;
            int jn = j + 4 + g;
            jn = (jn < cnt) ? jn : 0;
            int s2 = __shfl(sidx, jn);
            const float* sp2 = hn + (size_t)s2 * 128 + q * 8;
            h0 = *(const float4*)sp2;
            h1 = *(const float4*)(sp2 + 4);
            ns = norms[s2];
            float t = d0.x * c0.x + d0.y * c0.y + d0.z * c0.z + d0.w * c0.w
                    + d1.x * c1.x + d1.y * c1.y + d1.z * c1.z + d1.w * c1.w;
            t = gsum16(t);
            if (j + g < cnt) {
                float av = (t < THR) ? 1e-6f : t;
                denom += av;
                float w = av * cn;
                a0.x += w * c0.x; a0.y += w * c0.y; a0.z += w * c0.z; a0.w += w * c0.w;
                a1.x += w * c1.x; a1.y += w * c1.y; a1.z += w * c1.z; a1.w += w * c1.w;
            }
        }
    }
    // reduce the 4 groups
    #pragma unroll
    for (int o = 16; o < 64; o <<= 1) {
        a0.x += __shfl_xor(a0.x, o); a0.y += __shfl_xor(a0.y, o);
        a0.z += __shfl_xor(a0.z, o); a0.w += __shfl_xor(a0.w, o);
        a1.x += __shfl_xor(a1.x, o); a1.y += __shfl_xor(a1.y, o);
        a1.z += __shfl_xor(a1.z, o); a1.w += __shfl_xor(a1.w, o);
        denom += __shfl_xor(denom, o);
    }
    // self loop
    float a = (p < THR) ? 1e-6f : p;
    denom += a;
    float w = a * nd;
    a0.x += w * d0.x; a0.y += w * d0.y; a0.z += w * d0.z; a0.w += w * d0.w;
    a1.x += w * d1.x; a1.y += w * d1.y; a1.z += w * d1.z; a1.w += w * d1.w;
    if (g == 0) {
        float inv = 1.0f / denom;
        float4 o0 = {a0.x * inv, a0.y * inv, a0.z * inv, a0.w * inv};
        float4 o1 = {a1.x * inv, a1.y * inv, a1.z * inv, a1.w * inv};
        *(float4*)(r + (size_t)node * 128 + q * 8) = o0;
        *(float4*)(r + (size_t)node * 128 + q * 8 + 4) = o1;
    }
}

// ---------------- GEMM [M][128]@[128][128] + bias + LN + ReLU + re-normalize ----------------
__global__ void gemm_ln_k(const float* __restrict__ A, const float* __restrict__ B,
                          const float* __restrict__ bias, const float* __restrict__ g,
                          const float* __restrict__ be, float* __restrict__ hn,
                          float* __restrict__ norms, int M) {
    __shared__ float sA[64][33];
    __shared__ float sB[32][136];
    int row0 = blockIdx.x * 64;
    int tid = threadIdx.x;
    int tx = tid & 15, ty = tid >> 4;
    float acc[4][8];
    #pragma unroll
    for (int r = 0; r < 4; ++r)
        #pragma unroll
        for (int j = 0; j < 8; ++j) acc[r][j] = 0.f;

    for (int k0 = 0; k0 < 128; k0 += 32) {
        for (int i = tid; i < 64 * 32; i += 256) {
            int r = i >> 5, c = i & 31;
            sA[r][c] = (row0 + r < M) ? A[(size_t)(row0 + r) * 128 + k0 + c] : 0.f;
        }
        for (int i = tid; i < 32 * 128; i += 256) {
            int r = i >> 7, c = i & 127;
            sB[r][c] = B[(size_t)(k0 + r) * 128 + c];
        }
        __syncthreads();
        #pragma unroll
        for (int kk = 0; kk < 32; ++kk) {
            float4 bb0 = *(const float4*)&sB[kk][tx * 8];
            float4 bb1 = *(const float4*)&sB[kk][tx * 8 + 4];
            #pragma unroll
            for (int r = 0; r < 4; ++r) {
                float a = sA[ty * 4 + r][kk];
                acc[r][0] += a * bb0.x; acc[r][1] += a * bb0.y;
                acc[r][2] += a * bb0.z; acc[r][3] += a * bb0.w;
                acc[r][4] += a * bb1.x; acc[r][5] += a * bb1.y;
                acc[r][6] += a * bb1.z; acc[r][7] += a * bb1.w;
            }
        }
        __syncthreads();
    }
    float4 b4a = *(const float4*)(bias + tx * 8);
    float4 b4b = *(const float4*)(bias + tx * 8 + 4);
    float4 g4a = *(const float4*)(g + tx * 8);
    float4 g4b = *(const float4*)(g + tx * 8 + 4);
    float4 e4a = *(const float4*)(be + tx * 8);
    float4 e4b = *(const float4*)(be + tx * 8 + 4);
    #pragma unroll
    for (int r = 0; r < 4; ++r) {
        int row = row0 + ty * 4 + r;
        float o[8];
        float ls = 0.f;
        #pragma unroll
        for (int j = 0; j < 8; ++j) {
            o[j] = acc[r][j] + (j < 4 ? (&b4a.x)[j] : (&b4b.x)[j - 4]);
            ls += o[j];
        }
        float m = gsum16(ls) * (1.0f / 128.f);
        float vv = 0.f;
        float d[8];
        #pragma unroll
        for (int j = 0; j < 8; ++j) {
            d[j] = o[j] - m;
            vv += d[j] * d[j];
        }
        float var = gsum16(vv) * (1.0f / 128.f);
        float rs = rsqrtf(var + LN_EPS);
        float y[8];
        float ss = 0.f;
        #pragma unroll
        for (int j = 0; j < 8; ++j) {
            float gj = (j < 4 ? (&g4a.x)[j] : (&g4b.x)[j - 4]);
            float ej = (j < 4 ? (&e4a.x)[j] : (&e4b.x)[j - 4]);
            y[j] = fmaxf(d[j] * rs * gj + ej, 0.f);
            ss += y[j] * y[j];
        }
        float sst = gsum16(ss);
        float nrm = sqrtf(sst);
        float inv = 1.0f / fmaxf(nrm, COS_EPS);
        if (row < M) {
            float4 o0 = {y[0] * inv, y[1] * inv, y[2] * inv, y[3] * inv};
            float4 o1 = {y[4] * inv, y[5] * inv, y[6] * inv, y[7] * inv};
            *(float4*)(hn + (size_t)row * 128 + tx * 8) = o0;
            *(float4*)(hn + (size_t)row * 128 + tx * 8 + 4) = o1;
            if (tx == 0) norms[row] = nrm;
        }
    }
}

// ---------------- GEMM [M][128]@[128][64] + bias + log_softmax -> out ----------------
__global__ void gemm_lsm_k(const float* __restrict__ A, const float* __restrict__ B,
                           const float* __restrict__ bias, float* __restrict__ out, int M) {
    __shared__ float sA[64][33];
    __shared__ float sB[32][72];
    int row0 = blockIdx.x * 64;
    int tid = threadIdx.x;
    int tx = tid & 7, ty = tid >> 3;
    float acc[2][8];
    #pragma unroll
    for (int r = 0; r < 2; ++r)
        #pragma unroll
        for (int j = 0; j < 8; ++j) acc[r][j] = 0.f;

    for (int k0 = 0; k0 < 128; k0 += 32) {
        for (int i = tid; i < 64 * 32; i += 256) {
            int r = i >> 5, c = i & 31;
            sA[r][c] = (row0 + r < M) ? A[(size_t)(row0 + r) * 128 + k0 + c] : 0.f;
        }
        for (int i = tid; i < 32 * 64; i += 256) {
            int r = i >> 6, c = i & 63;
            sB[r][c] = B[(size_t)(k0 + r) * 64 + c];
        }
        __syncthreads();
        #pragma unroll
        for (int kk = 0; kk < 32; ++kk) {
            float4 bb0 = *(const float4*)&sB[kk][tx * 8];
            float4 bb1 = *(const float4*)&sB[kk][tx * 8 + 4];
            #pragma unroll
            for (int r = 0; r < 2; ++r) {
                float a = sA[ty * 2 + r][kk];
                acc[r][0] += a * bb0.x; acc[r][1] += a * bb0.y;
                acc[r][2] += a * bb0.z; acc[r][3] += a * bb0.w;
                acc[r][4] += a * bb1.x; acc[r][5] += a * bb1.y;
                acc[r][6] += a * bb1.z; acc[r][7] += a * bb1.w;
            }
        }
        __syncthreads();
    }
    float4 b4a = *(const float4*)(bias + tx * 8);
    float4 b4b = *(const float4*)(bias + tx * 8 + 4);
    #pragma unroll
    for (int r = 0; r < 2; ++r) {
        int row = row0 + ty * 2 + r;
        float v[8];
        float mx = -1e30f;
        #pragma unroll
        for (int j = 0; j < 8; ++j) {
            v[j] = acc[r][j] + (j < 4 ? (&b4a.x)[j] : (&b4b.x)[j - 4]);
            mx = fmaxf(mx, v[j]);
        }
        float m = gmax8(mx);
        float es = 0.f;
        #pragma unroll
        for (int j = 0; j < 8; ++j) es += __expf(v[j] - m);
        float s = gsum8(es);
        float ls = logf(s);
        if (row < M) {
            float4 o0 = {v[0] - m - ls, v[1] - m - ls, v[2] - m - ls, v[3] - m - ls};
            float4 o1 = {v[4] - m - ls, v[5] - m - ls, v[6] - m - ls, v[7] - m - ls};
            *(float4*)(out + (size_t)row * 64 + tx * 8) = o0;
            *(float4*)(out + (size_t)row * 64 + tx * 8 + 4) = o1;
        }
    }
}

extern "C" void kernel_launch(void* const* d_in, const int* in_sizes, int n_in,
                              void* d_out, int out_size, void* d_ws, size_t ws_size,
                              hipStream_t stream) {
    const float* x  = (const float*)d_in[0];
    const int* ei   = (const int*)d_in[1];
    const float* W0 = (const float*)d_in[2];
    const float* b0 = (const float*)d_in[3];
    const float* W1 = (const float*)d_in[4];
    const float* b1 = (const float*)d_in[5];
    const float* W2 = (const float*)d_in[6];
    const float* b2 = (const float*)d_in[7];
    const float* g1 = (const float*)d_in[8];
    const float* be1 = (const float*)d_in[9];
    const float* g2 = (const float*)d_in[10];
    const float* be2 = (const float*)d_in[11];

    const int N = in_sizes[0] / 128;
    const int E = in_sizes[1] / 2;
    const int* src = ei;
    const int* dst = ei + E;
    const int ntot = N + 1;
    const int nscan = (ntot + 1023) / 1024;

    size_t off = 0;
    auto carve = [&](size_t bytes) {
        void* p = (char*)d_ws + off;
        off += (bytes + 255) & ~(size_t)255;
        return p;
    };
    float* bufA   = (float*)carve((size_t)N * 128 * 4);
    float* bufB   = (float*)carve((size_t)N * 128 * 4);
    float* nA     = (float*)carve((size_t)N * 4);
    float* nB     = (float*)carve((size_t)N * 4);
    int* counts   = (int*)carve((size_t)ntot * 4);
    int* offs     = (int*)carve((size_t)ntot * 4);
    int* partials = (int*)carve((size_t)256 * 4);
    int* csr      = (int*)carve((size_t)E * 4);

    // CSR by destination
    hipMemsetAsync(counts, 0, (size_t)ntot * 4, stream);
    count_k<<<(E + 255) / 256, 256, 0, stream>>>(dst, E, counts);
    scan1_k<<<nscan, 256, 0, stream>>>(counts, partials, ntot);
    scan2_k<<<1, 64, 0, stream>>>(partials, nscan);
    scan3_k<<<nscan, 256, 0, stream>>>(counts, partials, offs, ntot);
    scatter_k<<<(E + 255) / 256, 256, 0, stream>>>(src, dst, E, counts, csr);

    const int gridN4 = (N + 3) / 4;
    const int gridG = (N + 63) / 64;

    // ---- layer 0
    normpack_k<<<gridN4, 256, 0, stream>>>(x, bufA, nA, N);
    agg_k<<<gridN4, 256, 0, stream>>>(bufA, nA, offs, csr, bufB, N);
    gemm_ln_k<<<gridG, 256, 0, stream>>>(bufB, W0, b0, g1, be1, bufB, nB, N);

    // ---- layer 1
    agg_k<<<gridN4, 256, 0, stream>>>(bufB, nB, offs, csr, bufA, N);
    gemm_ln_k<<<gridG, 256, 0, stream>>>(bufA, W1, b1, g2, be2, bufA, nA, N);

    // ---- layer 2
    agg_k<<<gridN4, 256, 0, stream>>>(bufA, nA, offs, csr, bufB, N);
    gemm_lsm_k<<<gridG, 256, 0, stream>>>(bufB, W2, b2, (float*)d_out, N);
}

// Round 5
// 360.558 us; speedup vs baseline: 2.2149x; 1.1593x over previous
//
#include <hip/hip_runtime.h>
#include <hip/hip_bf16.h>

#define THR 0.1f
#define COS_EPS 1e-8f
#define LN_EPS 1e-5f

typedef short bfx8 __attribute__((ext_vector_type(8)));
typedef float fx4 __attribute__((ext_vector_type(4)));

__device__ __forceinline__ float wave_sum(float v) {
    #pragma unroll
    for (int o = 1; o < 64; o <<= 1) v += __shfl_xor(v, o);
    return v;
}
__device__ __forceinline__ float gsum16(float v) {
    #pragma unroll
    for (int o = 1; o < 16; o <<= 1) v += __shfl_xor(v, o);
    return v;
}
__device__ __forceinline__ float gmax16(float v) {
    #pragma unroll
    for (int o = 1; o < 16; o <<= 1) v = fmaxf(v, __shfl_xor(v, o));
    return v;
}

__device__ __forceinline__ unsigned short f2bf(float f) {
    unsigned int u = __float_as_uint(f);
    unsigned int r = (u + 0x7FFFu + ((u >> 16) & 1u)) >> 16;
    return (unsigned short)r;
}
__device__ __forceinline__ float bf2f(unsigned short h) {
    return __uint_as_float(((unsigned int)h) << 16);
}

// ---------------- CSR build ----------------
__global__ void count_k(const int* __restrict__ dst, int E, int* __restrict__ counts) {
    int e = blockIdx.x * 256 + threadIdx.x;
    if (e < E) atomicAdd(&counts[dst[e]], 1);
}

__global__ void scan1_k(const int* __restrict__ counts, int* __restrict__ partials, int ntot) {
    int base = blockIdx.x * 1024;
    int t = threadIdx.x;
    int s = 0;
    #pragma unroll
    for (int i = 0; i < 4; ++i) {
        int idx = base + t + i * 256;
        if (idx < ntot) s += counts[idx];
    }
    s = (int)wave_sum((float)s);
    __shared__ int ws[4];
    if ((t & 63) == 0) ws[t >> 6] = s;
    __syncthreads();
    if (t == 0) partials[blockIdx.x] = ws[0] + ws[1] + ws[2] + ws[3];
}

__global__ void scan2_k(int* __restrict__ partials, int nb) {
    int t = threadIdx.x;
    int v = (t < nb) ? partials[t] : 0;
    int orig = v;
    #pragma unroll
    for (int o = 1; o < 64; o <<= 1) {
        int u = __shfl_up(v, o);
        if (t >= o) v += u;
    }
    if (t < nb) partials[t] = v - orig;
}

__global__ void scan3_k(int* __restrict__ counts, const int* __restrict__ partials,
                        int* __restrict__ offs, int ntot) {
    int base = blockIdx.x * 1024;
    int t = threadIdx.x;
    int lane = t & 63, wid = t >> 6;
    int idx = base + t * 4;
    int c[4];
    #pragma unroll
    for (int k = 0; k < 4; ++k) c[k] = (idx + k < ntot) ? counts[idx + k] : 0;
    int s = c[0] + c[1] + c[2] + c[3];
    int sc = s;
    #pragma unroll
    for (int o = 1; o < 64; o <<= 1) {
        int u = __shfl_up(sc, o);
        if (lane >= o) sc += u;
    }
    __shared__ int wsum[4];
    if (lane == 63) wsum[wid] = sc;
    __syncthreads();
    int add = partials[blockIdx.x];
    for (int w = 0; w < wid; ++w) add += wsum[w];
    int ex = add + sc - s;
    #pragma unroll
    for (int k = 0; k < 4; ++k) {
        if (idx + k < ntot) {
            offs[idx + k] = ex;
            counts[idx + k] = ex;
            ex += c[k];
        }
    }
}

__global__ void scatter_k(const int* __restrict__ src, const int* __restrict__ dst, int E,
                          int* __restrict__ cursor, int* __restrict__ csr_src) {
    int e = blockIdx.x * 256 + threadIdx.x;
    if (e < E) {
        int p = atomicAdd(&cursor[dst[e]], 1);
        csr_src[p] = src[e];
    }
}

// ---------------- normalize x -> hn + norms ----------------
__global__ void normpack_k(const float* __restrict__ h, float* __restrict__ hn,
                           float* __restrict__ norms, int n) {
    int node = (blockIdx.x * blockDim.x + threadIdx.x) >> 6;
    int lane = threadIdx.x & 63;
    if (node >= n) return;
    float2 v = *(const float2*)(h + (size_t)node * 128 + lane * 2);
    float ss = wave_sum(v.x * v.x + v.y * v.y);
    float nrm = sqrtf(ss);
    float inv = 1.0f / fmaxf(nrm, COS_EPS);
    float2 o = {v.x * inv, v.y * inv};
    *(float2*)(hn + (size_t)node * 128 + lane * 2) = o;
    if (lane == 0) norms[node] = nrm;
}

// ---------------- aggregation: 4 groups x 16 lanes, depth-2 prefetch ----------------
__global__ void agg_k(const float* __restrict__ hn, const float* __restrict__ norms,
                      const int* __restrict__ offs, const int* __restrict__ csr,
                      float* __restrict__ r, int n) {
    int node = (blockIdx.x * blockDim.x + threadIdx.x) >> 6;
    int lane = threadIdx.x & 63;
    if (node >= n) return;
    int g = lane >> 4;
    int q = lane & 15;
    const float* myrow = hn + (size_t)node * 128 + q * 8;
    float4 d0 = *(const float4*)myrow;
    float4 d1 = *(const float4*)(myrow + 4);
    float nd = norms[node];
    float p = d0.x * d0.x + d0.y * d0.y + d0.z * d0.z + d0.w * d0.w
            + d1.x * d1.x + d1.y * d1.y + d1.z * d1.z + d1.w * d1.w;
    p = gsum16(p);
    float4 a0 = {0.f, 0.f, 0.f, 0.f}, a1 = {0.f, 0.f, 0.f, 0.f};
    float denom = 0.f;
    int b = offs[node], e = offs[node + 1];
    for (int i0 = b; i0 < e; i0 += 64) {
        int cnt = e - i0;
        if (cnt > 64) cnt = 64;
        int sidx = csr[i0 + (lane < cnt ? lane : 0)];
        int jp0 = (g < cnt) ? g : 0;
        int s0 = __shfl(sidx, jp0);
        const float* sp0 = hn + (size_t)s0 * 128 + q * 8;
        float4 e0a = *(const float4*)sp0, e0b = *(const float4*)(sp0 + 4);
        float e0n = norms[s0];
        int jp1 = 4 + g;
        jp1 = (jp1 < cnt) ? jp1 : 0;
        int s1 = __shfl(sidx, jp1);
        const float* sp1 = hn + (size_t)s1 * 128 + q * 8;
        float4 e1a = *(const float4*)sp1, e1b = *(const float4*)(sp1 + 4);
        float e1n = norms[s1];
        for (int j = 0; j < cnt; j += 4) {
            float4 c0 = e0a, c1 = e0b;
            float cn = e0n;
            e0a = e1a; e0b = e1b; e0n = e1n;
            int jn = j + 8 + g;
            jn = (jn < cnt) ? jn : 0;
            int s2 = __shfl(sidx, jn);
            const float* sp2 = hn + (size_t)s2 * 128 + q * 8;
            e1a = *(const float4*)sp2;
            e1b = *(const float4*)(sp2 + 4);
            e1n = norms[s2];
            float t = d0.x * c0.x + d0.y * c0.y + d0.z * c0.z + d0.w * c0.w
                    + d1.x * c1.x + d1.y * c1.y + d1.z * c1.z + d1.w * c1.w;
            t = gsum16(t);
            if (j + g < cnt) {
                float av = (t < THR) ? 1e-6f : t;
                denom += av;
                float w = av * cn;
                a0.x += w * c0.x; a0.y += w * c0.y; a0.z += w * c0.z; a0.w += w * c0.w;
                a1.x += w * c1.x; a1.y += w * c1.y; a1.z += w * c1.z; a1.w += w * c1.w;
            }
        }
    }
    #pragma unroll
    for (int o = 16; o < 64; o <<= 1) {
        a0.x += __shfl_xor(a0.x, o); a0.y += __shfl_xor(a0.y, o);
        a0.z += __shfl_xor(a0.z, o); a0.w += __shfl_xor(a0.w, o);
        a1.x += __shfl_xor(a1.x, o); a1.y += __shfl_xor(a1.y, o);
        a1.z += __shfl_xor(a1.z, o); a1.w += __shfl_xor(a1.w, o);
        denom += __shfl_xor(denom, o);
    }
    float a = (p < THR) ? 1e-6f : p;
    denom += a;
    float w = a * nd;
    a0.x += w * d0.x; a0.y += w * d0.y; a0.z += w * d0.z; a0.w += w * d0.w;
    a1.x += w * d1.x; a1.y += w * d1.y; a1.z += w * d1.z; a1.w += w * d1.w;
    if (g == 0) {
        float inv = 1.0f / denom;
        float4 o0 = {a0.x * inv, a0.y * inv, a0.z * inv, a0.w * inv};
        float4 o1 = {a1.x * inv, a1.y * inv, a1.z * inv, a1.w * inv};
        *(float4*)(r + (size_t)node * 128 + q * 8) = o0;
        *(float4*)(r + (size_t)node * 128 + q * 8 + 4) = o1;
    }
}

// ---------------- W prep: split fp32 W[k][col] into 3 bf16 planes in B-frag order ----
// plane element ((ks*CF+cf)*64 + lane)*8 + j  =  W[ks*32 + (lane>>4)*8 + j][cf*16 + (lane&15)]
template <int CF>
__global__ __launch_bounds__(256) void wprep_k(const float* __restrict__ W,
                                               unsigned short* __restrict__ P) {
    const int PLANE = CF * 2048;
    int t = blockIdx.x * 256 + threadIdx.x;
    if (t >= 4 * CF * 64) return;
    int lane = t & 63, fr = t >> 6;
    int cf = fr % CF, ks = fr / CF;
    int col = cf * 16 + (lane & 15);
    int k0 = ks * 32 + (lane >> 4) * 8;
    size_t base = (size_t)fr * 512 + (size_t)lane * 8;
    #pragma unroll
    for (int j = 0; j < 8; ++j) {
        float x = W[(size_t)(k0 + j) * (CF * 16) + col];
        unsigned short h = f2bf(x);
        float fh = bf2f(h);
        float r1 = x - fh;
        unsigned short m = f2bf(r1);
        float fm = bf2f(m);
        unsigned short lo = f2bf(r1 - fm);
        P[base + j] = h;
        P[PLANE + base + j] = m;
        P[2 * PLANE + base + j] = lo;
    }
}

// ---------------- MFMA core: acc[CF] += A(16x128 fp32, 3-way bf16 split) @ Bplanes ----
template <int CF>
__device__ __forceinline__ void mfma_core(const float* __restrict__ arow,
                                          const unsigned short* __restrict__ P,
                                          int lane, fx4* acc) {
    const int PLANE = CF * 2048;
    float ast[32];
    #pragma unroll
    for (int ks = 0; ks < 4; ++ks) {
        float4 u0 = *(const float4*)(arow + ks * 32);
        float4 u1 = *(const float4*)(arow + ks * 32 + 4);
        ast[ks * 8 + 0] = u0.x; ast[ks * 8 + 1] = u0.y;
        ast[ks * 8 + 2] = u0.z; ast[ks * 8 + 3] = u0.w;
        ast[ks * 8 + 4] = u1.x; ast[ks * 8 + 5] = u1.y;
        ast[ks * 8 + 6] = u1.z; ast[ks * 8 + 7] = u1.w;
    }
    #pragma unroll
    for (int ks = 0; ks < 4; ++ks) {
        bfx8 ah, am, al;
        #pragma unroll
        for (int j = 0; j < 8; ++j) {
            float x = ast[ks * 8 + j];
            unsigned short h = f2bf(x);
            float fh = bf2f(h);
            float r1 = x - fh;
            unsigned short m = f2bf(r1);
            float fm = bf2f(m);
            unsigned short lo = f2bf(r1 - fm);
            ah[j] = (short)h; am[j] = (short)m; al[j] = (short)lo;
        }
        #pragma unroll
        for (int cb = 0; cb < CF; cb += 4) {
            bfx8 bh[4], bm[4], bl[4];
            #pragma unroll
            for (int q = 0; q < 4; ++q) {
                size_t base = ((size_t)(ks * CF + cb + q) * 64 + lane) * 8;
                bh[q] = *(const bfx8*)(P + base);
                bm[q] = *(const bfx8*)(P + PLANE + base);
                bl[q] = *(const bfx8*)(P + 2 * PLANE + base);
            }
            #pragma unroll
            for (int q = 0; q < 4; ++q)
                acc[cb + q] = __builtin_amdgcn_mfma_f32_16x16x32_bf16(ah, bh[q], acc[cb + q], 0, 0, 0);
            #pragma unroll
            for (int q = 0; q < 4; ++q)
                acc[cb + q] = __builtin_amdgcn_mfma_f32_16x16x32_bf16(ah, bm[q], acc[cb + q], 0, 0, 0);
            #pragma unroll
            for (int q = 0; q < 4; ++q)
                acc[cb + q] = __builtin_amdgcn_mfma_f32_16x16x32_bf16(am, bh[q], acc[cb + q], 0, 0, 0);
            #pragma unroll
            for (int q = 0; q < 4; ++q)
                acc[cb + q] = __builtin_amdgcn_mfma_f32_16x16x32_bf16(ah, bl[q], acc[cb + q], 0, 0, 0);
            #pragma unroll
            for (int q = 0; q < 4; ++q)
                acc[cb + q] = __builtin_amdgcn_mfma_f32_16x16x32_bf16(am, bm[q], acc[cb + q], 0, 0, 0);
            #pragma unroll
            for (int q = 0; q < 4; ++q)
                acc[cb + q] = __builtin_amdgcn_mfma_f32_16x16x32_bf16(al, bh[q], acc[cb + q], 0, 0, 0);
        }
    }
}

// ---------------- MFMA GEMM + bias + LN + ReLU + renormalize (FOUT=128) ----------------
__global__ __launch_bounds__(256) void mgemm_ln_k(const float* __restrict__ A,
    const unsigned short* __restrict__ P, const float* __restrict__ bias,
    const float* __restrict__ g, const float* __restrict__ be,
    float* __restrict__ hn, float* __restrict__ norms, int nw, int M) {
    const int CF = 8;
    int wid = blockIdx.x * 4 + (threadIdx.x >> 6);
    if (wid >= nw) return;
    int lane = threadIdx.x & 63;
    int rsel = lane & 15, kg = lane >> 4;
    int arowi = wid * 16 + rsel;
    if (arowi >= M) arowi = M - 1;
    const float* arow = A + (size_t)arowi * 128 + kg * 8;
    fx4 acc[CF];
    #pragma unroll
    for (int c = 0; c < CF; ++c) acc[c] = (fx4){0.f, 0.f, 0.f, 0.f};
    mfma_core<CF>(arow, P, lane, acc);
    float bi[CF], gm[CF], bb[CF];
    #pragma unroll
    for (int c = 0; c < CF; ++c) {
        int col = c * 16 + rsel;
        bi[c] = bias[col]; gm[c] = g[col]; bb[c] = be[col];
    }
    #pragma unroll
    for (int r = 0; r < 4; ++r) {
        int row = wid * 16 + kg * 4 + r;
        float o[CF], s = 0.f;
        #pragma unroll
        for (int c = 0; c < CF; ++c) { o[c] = acc[c][r] + bi[c]; s += o[c]; }
        float mean = gsum16(s) * (1.f / 128.f);
        float vv = 0.f;
        #pragma unroll
        for (int c = 0; c < CF; ++c) { o[c] -= mean; vv += o[c] * o[c]; }
        float var = gsum16(vv) * (1.f / 128.f);
        float rs = rsqrtf(var + LN_EPS);
        float ss = 0.f;
        #pragma unroll
        for (int c = 0; c < CF; ++c) {
            o[c] = fmaxf(o[c] * rs * gm[c] + bb[c], 0.f);
            ss += o[c] * o[c];
        }
        float nrm = sqrtf(gsum16(ss));
        float inv = 1.f / fmaxf(nrm, COS_EPS);
        if (row < M) {
            #pragma unroll
            for (int c = 0; c < CF; ++c) hn[(size_t)row * 128 + c * 16 + rsel] = o[c] * inv;
            if (rsel == 0) norms[row] = nrm;
        }
    }
}

// ---------------- MFMA GEMM + bias + log_softmax (FOUT=64) ----------------
__global__ __launch_bounds__(256) void mgemm_lsm_k(const float* __restrict__ A,
    const unsigned short* __restrict__ P, const float* __restrict__ bias,
    float* __restrict__ out, int nw, int M) {
    const int CF = 4;
    int wid = blockIdx.x * 4 + (threadIdx.x >> 6);
    if (wid >= nw) return;
    int lane = threadIdx.x & 63;
    int rsel = lane & 15, kg = lane >> 4;
    int arowi = wid * 16 + rsel;
    if (arowi >= M) arowi = M - 1;
    const float* arow = A + (size_t)arowi * 128 + kg * 8;
    fx4 acc[CF];
    #pragma unroll
    for (int c = 0; c < CF; ++c) acc[c] = (fx4){0.f, 0.f, 0.f, 0.f};
    mfma_core<CF>(arow, P, lane, acc);
    float bi[CF];
    #pragma unroll
    for (int c = 0; c < CF; ++c) bi[c] = bias[c * 16 + rsel];
    #pragma unroll
    for (int r = 0; r < 4; ++r) {
        int row = wid * 16 + kg * 4 + r;
        float v[CF], mx = -1e30f;
        #pragma unroll
        for (int c = 0; c < CF; ++c) { v[c] = acc[c][r] + bi[c]; mx = fmaxf(mx, v[c]); }
        float m = gmax16(mx);
        float es = 0.f;
        #pragma unroll
        for (int c = 0; c < CF; ++c) es += __expf(v[c] - m);
        float s = gsum16(es);
        float ls = logf(s);
        if (row < M) {
            #pragma unroll
            for (int c = 0; c < CF; ++c) out[(size_t)row * 64 + c * 16 + rsel] = v[c] - m - ls;
        }
    }
}

extern "C" void kernel_launch(void* const* d_in, const int* in_sizes, int n_in,
                              void* d_out, int out_size, void* d_ws, size_t ws_size,
                              hipStream_t stream) {
    const float* x  = (const float*)d_in[0];
    const int* ei   = (const int*)d_in[1];
    const float* W0 = (const float*)d_in[2];
    const float* b0 = (const float*)d_in[3];
    const float* W1 = (const float*)d_in[4];
    const float* b1 = (const float*)d_in[5];
    const float* W2 = (const float*)d_in[6];
    const float* b2 = (const float*)d_in[7];
    const float* g1 = (const float*)d_in[8];
    const float* be1 = (const float*)d_in[9];
    const float* g2 = (const float*)d_in[10];
    const float* be2 = (const float*)d_in[11];

    const int N = in_sizes[0] / 128;
    const int E = in_sizes[1] / 2;
    const int* src = ei;
    const int* dst = ei + E;
    const int ntot = N + 1;
    const int nscan = (ntot + 1023) / 1024;

    size_t off = 0;
    auto carve = [&](size_t bytes) {
        void* p = (char*)d_ws + off;
        off += (bytes + 255) & ~(size_t)255;
        return p;
    };
    float* bufA   = (float*)carve((size_t)N * 128 * 4);
    float* bufB   = (float*)carve((size_t)N * 128 * 4);
    float* nA     = (float*)carve((size_t)N * 4);
    float* nB     = (float*)carve((size_t)N * 4);
    int* counts   = (int*)carve((size_t)ntot * 4);
    int* offs     = (int*)carve((size_t)ntot * 4);
    int* partials = (int*)carve((size_t)256 * 4);
    int* csr      = (int*)carve((size_t)E * 4);
    unsigned short* w0p = (unsigned short*)carve((size_t)3 * 16384 * 2);
    unsigned short* w1p = (unsigned short*)carve((size_t)3 * 16384 * 2);
    unsigned short* w2p = (unsigned short*)carve((size_t)3 * 8192 * 2);

    // W plane prep (independent of everything else)
    wprep_k<8><<<8, 256, 0, stream>>>(W0, w0p);
    wprep_k<8><<<8, 256, 0, stream>>>(W1, w1p);
    wprep_k<4><<<4, 256, 0, stream>>>(W2, w2p);

    // CSR by destination
    hipMemsetAsync(counts, 0, (size_t)ntot * 4, stream);
    count_k<<<(E + 255) / 256, 256, 0, stream>>>(dst, E, counts);
    scan1_k<<<nscan, 256, 0, stream>>>(counts, partials, ntot);
    scan2_k<<<1, 64, 0, stream>>>(partials, nscan);
    scan3_k<<<nscan, 256, 0, stream>>>(counts, partials, offs, ntot);
    scatter_k<<<(E + 255) / 256, 256, 0, stream>>>(src, dst, E, counts, csr);

    const int gridN4 = (N + 3) / 4;
    const int nwaves = (N + 15) / 16;
    const int gridW = (nwaves + 3) / 4;

    // ---- layer 0
    normpack_k<<<gridN4, 256, 0, stream>>>(x, bufA, nA, N);
    agg_k<<<gridN4, 256, 0, stream>>>(bufA, nA, offs, csr, bufB, N);
    mgemm_ln_k<<<gridW, 256, 0, stream>>>(bufB, w0p, b0, g1, be1, bufB, nB, nwaves, N);

    // ---- layer 1
    agg_k<<<gridN4, 256, 0, stream>>>(bufB, nB, offs, csr, bufA, N);
    mgemm_ln_k<<<gridW, 256, 0, stream>>>(bufA, w1p, b1, g2, be2, bufA, nA, nwaves, N);

    // ---- layer 2
    agg_k<<<gridN4, 256, 0, stream>>>(bufA, nA, offs, csr, bufB, N);
    mgemm_lsm_k<<<gridW, 256, 0, stream>>>(bufB, w2p, b2, (float*)d_out, nwaves, N);
}

// Round 8
// 350.239 us; speedup vs baseline: 2.2801x; 1.0295x over previous
//
#include <hip/hip_runtime.h>
#include <hip/hip_bf16.h>

#define THR 0.1f
#define COS_EPS 1e-8f
#define LN_EPS 1e-5f

typedef short bfx8 __attribute__((ext_vector_type(8)));
typedef float fx4 __attribute__((ext_vector_type(4)));

__device__ __forceinline__ float wave_sum(float v) {
    #pragma unroll
    for (int o = 1; o < 64; o <<= 1) v += __shfl_xor(v, o);
    return v;
}
__device__ __forceinline__ float gsum16(float v) {
    #pragma unroll
    for (int o = 1; o < 16; o <<= 1) v += __shfl_xor(v, o);
    return v;
}
__device__ __forceinline__ float gmax16(float v) {
    #pragma unroll
    for (int o = 1; o < 16; o <<= 1) v = fmaxf(v, __shfl_xor(v, o));
    return v;
}

__device__ __forceinline__ unsigned short f2bf(float f) {
    unsigned int u = __float_as_uint(f);
    unsigned int r = (u + 0x7FFFu + ((u >> 16) & 1u)) >> 16;
    return (unsigned short)r;
}
__device__ __forceinline__ float bf2f(unsigned short h) {
    return __uint_as_float(((unsigned int)h) << 16);
}

// ---------------- CSR build (integer-only: free to restructure) ----------------
__global__ void count_k(const int* __restrict__ dst, int E, int* __restrict__ counts) {
    int e = blockIdx.x * 256 + threadIdx.x;
    if (e < E) atomicAdd(&counts[dst[e]], 1);
}

// fused scan phase 1+2: per-1024-chunk sums; last block scans the <=64 partials
__global__ void scan12_k(const int* __restrict__ counts, int* __restrict__ partials,
                         int* __restrict__ done, int ntot, int nb) {
    int base = blockIdx.x * 1024;
    int t = threadIdx.x;
    int s = 0;
    #pragma unroll
    for (int i = 0; i < 4; ++i) {
        int idx = base + t + i * 256;
        if (idx < ntot) s += counts[idx];
    }
    s = (int)wave_sum((float)s);  // exact: partial sums << 2^24
    __shared__ int ws[4];
    __shared__ int amLast;
    if ((t & 63) == 0) ws[t >> 6] = s;
    __syncthreads();
    if (t == 0) {
        partials[blockIdx.x] = ws[0] + ws[1] + ws[2] + ws[3];
        __threadfence();
        amLast = (atomicAdd(done, 1) == (int)gridDim.x - 1);
    }
    __syncthreads();
    if (amLast && t < 64) {
        __threadfence();
        int v = (t < nb) ? partials[t] : 0;
        int orig = v;
        #pragma unroll
        for (int o = 1; o < 64; o <<= 1) {
            int u = __shfl_up(v, o);
            if (t >= o) v += u;
        }
        if (t < nb) partials[t] = v - orig;
    }
}

__global__ void scan3_k(int* __restrict__ counts, const int* __restrict__ partials,
                        int* __restrict__ offs, int ntot) {
    int base = blockIdx.x * 1024;
    int t = threadIdx.x;
    int lane = t & 63, wid = t >> 6;
    int idx = base + t * 4;
    int c[4];
    #pragma unroll
    for (int k = 0; k < 4; ++k) c[k] = (idx + k < ntot) ? counts[idx + k] : 0;
    int s = c[0] + c[1] + c[2] + c[3];
    int sc = s;
    #pragma unroll
    for (int o = 1; o < 64; o <<= 1) {
        int u = __shfl_up(sc, o);
        if (lane >= o) sc += u;
    }
    __shared__ int wsum[4];
    if (lane == 63) wsum[wid] = sc;
    __syncthreads();
    int add = partials[blockIdx.x];
    for (int w = 0; w < wid; ++w) add += wsum[w];
    int ex = add + sc - s;
    #pragma unroll
    for (int k = 0; k < 4; ++k) {
        if (idx + k < ntot) {
            offs[idx + k] = ex;
            counts[idx + k] = ex;
            ex += c[k];
        }
    }
}

__global__ void scatter_k(const int* __restrict__ src, const int* __restrict__ dst, int E,
                          int* __restrict__ cursor, int* __restrict__ csr_src) {
    int e = blockIdx.x * 256 + threadIdx.x;
    if (e < E) {
        int p = atomicAdd(&cursor[dst[e]], 1);
        csr_src[p] = src[e];
    }
}

// ---------------- normalize x -> hn + norms (FROZEN: byte-exact R5) ----------------
__global__ void normpack_k(const float* __restrict__ h, float* __restrict__ hn,
                           float* __restrict__ norms, int n) {
    int node = (blockIdx.x * blockDim.x + threadIdx.x) >> 6;
    int lane = threadIdx.x & 63;
    if (node >= n) return;
    float2 v = *(const float2*)(h + (size_t)node * 128 + lane * 2);
    float ss = wave_sum(v.x * v.x + v.y * v.y);
    float nrm = sqrtf(ss);
    float inv = 1.0f / fmaxf(nrm, COS_EPS);
    float2 o = {v.x * inv, v.y * inv};
    *(float2*)(hn + (size_t)node * 128 + lane * 2) = o;
    if (lane == 0) norms[node] = nrm;
}

// ---------------- aggregation (FROZEN: byte-exact R5 depth-2) ----------------
__global__ void agg_k(const float* __restrict__ hn, const float* __restrict__ norms,
                      const int* __restrict__ offs, const int* __restrict__ csr,
                      float* __restrict__ r, int n) {
    int node = (blockIdx.x * blockDim.x + threadIdx.x) >> 6;
    int lane = threadIdx.x & 63;
    if (node >= n) return;
    int g = lane >> 4;
    int q = lane & 15;
    const float* myrow = hn + (size_t)node * 128 + q * 8;
    float4 d0 = *(const float4*)myrow;
    float4 d1 = *(const float4*)(myrow + 4);
    float nd = norms[node];
    float p = d0.x * d0.x + d0.y * d0.y + d0.z * d0.z + d0.w * d0.w
            + d1.x * d1.x + d1.y * d1.y + d1.z * d1.z + d1.w * d1.w;
    p = gsum16(p);
    float4 a0 = {0.f, 0.f, 0.f, 0.f}, a1 = {0.f, 0.f, 0.f, 0.f};
    float denom = 0.f;
    int b = offs[node], e = offs[node + 1];
    for (int i0 = b; i0 < e; i0 += 64) {
        int cnt = e - i0;
        if (cnt > 64) cnt = 64;
        int sidx = csr[i0 + (lane < cnt ? lane : 0)];
        int jp0 = (g < cnt) ? g : 0;
        int s0 = __shfl(sidx, jp0);
        const float* sp0 = hn + (size_t)s0 * 128 + q * 8;
        float4 e0a = *(const float4*)sp0, e0b = *(const float4*)(sp0 + 4);
        float e0n = norms[s0];
        int jp1 = 4 + g;
        jp1 = (jp1 < cnt) ? jp1 : 0;
        int s1 = __shfl(sidx, jp1);
        const float* sp1 = hn + (size_t)s1 * 128 + q * 8;
        float4 e1a = *(const float4*)sp1, e1b = *(const float4*)(sp1 + 4);
        float e1n = norms[s1];
        for (int j = 0; j < cnt; j += 4) {
            float4 c0 = e0a, c1 = e0b;
            float cn = e0n;
            e0a = e1a; e0b = e1b; e0n = e1n;
            int jn = j + 8 + g;
            jn = (jn < cnt) ? jn : 0;
            int s2 = __shfl(sidx, jn);
            const float* sp2 = hn + (size_t)s2 * 128 + q * 8;
            e1a = *(const float4*)sp2;
            e1b = *(const float4*)(sp2 + 4);
            e1n = norms[s2];
            float t = d0.x * c0.x + d0.y * c0.y + d0.z * c0.z + d0.w * c0.w
                    + d1.x * c1.x + d1.y * c1.y + d1.z * c1.z + d1.w * c1.w;
            t = gsum16(t);
            if (j + g < cnt) {
                float av = (t < THR) ? 1e-6f : t;
                denom += av;
                float w = av * cn;
                a0.x += w * c0.x; a0.y += w * c0.y; a0.z += w * c0.z; a0.w += w * c0.w;
                a1.x += w * c1.x; a1.y += w * c1.y; a1.z += w * c1.z; a1.w += w * c1.w;
            }
        }
    }
    #pragma unroll
    for (int o = 16; o < 64; o <<= 1) {
        a0.x += __shfl_xor(a0.x, o); a0.y += __shfl_xor(a0.y, o);
        a0.z += __shfl_xor(a0.z, o); a0.w += __shfl_xor(a0.w, o);
        a1.x += __shfl_xor(a1.x, o); a1.y += __shfl_xor(a1.y, o);
        a1.z += __shfl_xor(a1.z, o); a1.w += __shfl_xor(a1.w, o);
        denom += __shfl_xor(denom, o);
    }
    // self loop
    float a = (p < THR) ? 1e-6f : p;
    denom += a;
    float w = a * nd;
    a0.x += w * d0.x; a0.y += w * d0.y; a0.z += w * d0.z; a0.w += w * d0.w;
    a1.x += w * d1.x; a1.y += w * d1.y; a1.z += w * d1.z; a1.w += w * d1.w;
    if (g == 0) {
        float inv = 1.0f / denom;
        float4 o0 = {a0.x * inv, a0.y * inv, a0.z * inv, a0.w * inv};
        float4 o1 = {a1.x * inv, a1.y * inv, a1.z * inv, a1.w * inv};
        *(float4*)(r + (size_t)node * 128 + q * 8) = o0;
        *(float4*)(r + (size_t)node * 128 + q * 8 + 4) = o1;
    }
}

// ---------------- W prep (value-pinned: integer rounding + exact subtractions) ----
template <int CF>
__device__ __forceinline__ void wprep_body(const float* __restrict__ W,
                                           unsigned short* __restrict__ P, int t) {
    const int PLANE = CF * 2048;
    if (t >= 4 * CF * 64) return;
    int lane = t & 63, fr = t >> 6;
    int cf = fr % CF, ks = fr / CF;
    int col = cf * 16 + (lane & 15);
    int k0 = ks * 32 + (lane >> 4) * 8;
    size_t base = (size_t)fr * 512 + (size_t)lane * 8;
    #pragma unroll
    for (int j = 0; j < 8; ++j) {
        float x = W[(size_t)(k0 + j) * (CF * 16) + col];
        unsigned short h = f2bf(x);
        float fh = bf2f(h);
        float r1 = x - fh;
        unsigned short m = f2bf(r1);
        float fm = bf2f(m);
        unsigned short lo = f2bf(r1 - fm);
        P[base + j] = h;
        P[PLANE + base + j] = m;
        P[2 * PLANE + base + j] = lo;
    }
}

__global__ __launch_bounds__(256) void wprep01_k(const float* __restrict__ W0,
                                                 const float* __restrict__ W1,
                                                 unsigned short* __restrict__ P0,
                                                 unsigned short* __restrict__ P1) {
    bool first = blockIdx.x < 8;
    const float* W = first ? W0 : W1;
    unsigned short* P = first ? P0 : P1;
    wprep_body<8>(W, P, (int)(blockIdx.x & 7) * 256 + threadIdx.x);
}

__global__ __launch_bounds__(256) void wprep2_k(const float* __restrict__ W,
                                                unsigned short* __restrict__ P) {
    wprep_body<4>(W, P, (int)blockIdx.x * 256 + threadIdx.x);
}

// ---------------- MFMA core (FROZEN: byte-exact R5) ----------------
template <int CF>
__device__ __forceinline__ void mfma_core(const float* __restrict__ arow,
                                          const unsigned short* __restrict__ P,
                                          int lane, fx4* acc) {
    const int PLANE = CF * 2048;
    float ast[32];
    #pragma unroll
    for (int ks = 0; ks < 4; ++ks) {
        float4 u0 = *(const float4*)(arow + ks * 32);
        float4 u1 = *(const float4*)(arow + ks * 32 + 4);
        ast[ks * 8 + 0] = u0.x; ast[ks * 8 + 1] = u0.y;
        ast[ks * 8 + 2] = u0.z; ast[ks * 8 + 3] = u0.w;
        ast[ks * 8 + 4] = u1.x; ast[ks * 8 + 5] = u1.y;
        ast[ks * 8 + 6] = u1.z; ast[ks * 8 + 7] = u1.w;
    }
    #pragma unroll
    for (int ks = 0; ks < 4; ++ks) {
        bfx8 ah, am, al;
        #pragma unroll
        for (int j = 0; j < 8; ++j) {
            float x = ast[ks * 8 + j];
            unsigned short h = f2bf(x);
            float fh = bf2f(h);
            float r1 = x - fh;
            unsigned short m = f2bf(r1);
            float fm = bf2f(m);
            unsigned short lo = f2bf(r1 - fm);
            ah[j] = (short)h; am[j] = (short)m; al[j] = (short)lo;
        }
        #pragma unroll
        for (int cb = 0; cb < CF; cb += 4) {
            bfx8 bh[4], bm[4], bl[4];
            #pragma unroll
            for (int q = 0; q < 4; ++q) {
                size_t base = ((size_t)(ks * CF + cb + q) * 64 + lane) * 8;
                bh[q] = *(const bfx8*)(P + base);
                bm[q] = *(const bfx8*)(P + PLANE + base);
                bl[q] = *(const bfx8*)(P + 2 * PLANE + base);
            }
            #pragma unroll
            for (int q = 0; q < 4; ++q)
                acc[cb + q] = __builtin_amdgcn_mfma_f32_16x16x32_bf16(ah, bh[q], acc[cb + q], 0, 0, 0);
            #pragma unroll
            for (int q = 0; q < 4; ++q)
                acc[cb + q] = __builtin_amdgcn_mfma_f32_16x16x32_bf16(ah, bm[q], acc[cb + q], 0, 0, 0);
            #pragma unroll
            for (int q = 0; q < 4; ++q)
                acc[cb + q] = __builtin_amdgcn_mfma_f32_16x16x32_bf16(am, bh[q], acc[cb + q], 0, 0, 0);
            #pragma unroll
            for (int q = 0; q < 4; ++q)
                acc[cb + q] = __builtin_amdgcn_mfma_f32_16x16x32_bf16(ah, bl[q], acc[cb + q], 0, 0, 0);
            #pragma unroll
            for (int q = 0; q < 4; ++q)
                acc[cb + q] = __builtin_amdgcn_mfma_f32_16x16x32_bf16(am, bm[q], acc[cb + q], 0, 0, 0);
            #pragma unroll
            for (int q = 0; q < 4; ++q)
                acc[cb + q] = __builtin_amdgcn_mfma_f32_16x16x32_bf16(al, bh[q], acc[cb + q], 0, 0, 0);
        }
    }
}

// ---------------- MFMA GEMM + bias + LN + ReLU + renormalize (FROZEN: R5) ----------------
__global__ __launch_bounds__(256) void mgemm_ln_k(const float* __restrict__ A,
    const unsigned short* __restrict__ P, const float* __restrict__ bias,
    const float* __restrict__ g, const float* __restrict__ be,
    float* __restrict__ hn, float* __restrict__ norms, int nw, int M) {
    const int CF = 8;
    int wid = blockIdx.x * 4 + (threadIdx.x >> 6);
    if (wid >= nw) return;
    int lane = threadIdx.x & 63;
    int rsel = lane & 15, kg = lane >> 4;
    int arowi = wid * 16 + rsel;
    if (arowi >= M) arowi = M - 1;
    const float* arow = A + (size_t)arowi * 128 + kg * 8;
    fx4 acc[CF];
    #pragma unroll
    for (int c = 0; c < CF; ++c) acc[c] = (fx4){0.f, 0.f, 0.f, 0.f};
    mfma_core<CF>(arow, P, lane, acc);
    float bi[CF], gm[CF], bb[CF];
    #pragma unroll
    for (int c = 0; c < CF; ++c) {
        int col = c * 16 + rsel;
        bi[c] = bias[col]; gm[c] = g[col]; bb[c] = be[col];
    }
    #pragma unroll
    for (int r = 0; r < 4; ++r) {
        int row = wid * 16 + kg * 4 + r;
        float o[CF], s = 0.f;
        #pragma unroll
        for (int c = 0; c < CF; ++c) { o[c] = acc[c][r] + bi[c]; s += o[c]; }
        float mean = gsum16(s) * (1.f / 128.f);
        float vv = 0.f;
        #pragma unroll
        for (int c = 0; c < CF; ++c) { o[c] -= mean; vv += o[c] * o[c]; }
        float var = gsum16(vv) * (1.f / 128.f);
        float rs = rsqrtf(var + LN_EPS);
        float ss = 0.f;
        #pragma unroll
        for (int c = 0; c < CF; ++c) {
            o[c] = fmaxf(o[c] * rs * gm[c] + bb[c], 0.f);
            ss += o[c] * o[c];
        }
        float nrm = sqrtf(gsum16(ss));
        float inv = 1.f / fmaxf(nrm, COS_EPS);
        if (row < M) {
            #pragma unroll
            for (int c = 0; c < CF; ++c) hn[(size_t)row * 128 + c * 16 + rsel] = o[c] * inv;
            if (rsel == 0) norms[row] = nrm;
        }
    }
}

// ---------------- MFMA GEMM + bias + log_softmax (FROZEN: R5) ----------------
__global__ __launch_bounds__(256) void mgemm_lsm_k(const float* __restrict__ A,
    const unsigned short* __restrict__ P, const float* __restrict__ bias,
    float* __restrict__ out, int nw, int M) {
    const int CF = 4;
    int wid = blockIdx.x * 4 + (threadIdx.x >> 6);
    if (wid >= nw) return;
    int lane = threadIdx.x & 63;
    int rsel = lane & 15, kg = lane >> 4;
    int arowi = wid * 16 + rsel;
    if (arowi >= M) arowi = M - 1;
    const float* arow = A + (size_t)arowi * 128 + kg * 8;
    fx4 acc[CF];
    #pragma unroll
    for (int c = 0; c < CF; ++c) acc[c] = (fx4){0.f, 0.f, 0.f, 0.f};
    mfma_core<CF>(arow, P, lane, acc);
    float bi[CF];
    #pragma unroll
    for (int c = 0; c < CF; ++c) bi[c] = bias[c * 16 + rsel];
    #pragma unroll
    for (int r = 0; r < 4; ++r) {
        int row = wid * 16 + kg * 4 + r;
        float v[CF], mx = -1e30f;
        #pragma unroll
        for (int c = 0; c < CF; ++c) { v[c] = acc[c][r] + bi[c]; mx = fmaxf(mx, v[c]); }
        float m = gmax16(mx);
        float es = 0.f;
        #pragma unroll
        for (int c = 0; c < CF; ++c) es += __expf(v[c] - m);
        float s = gsum16(es);
        float ls = logf(s);
        if (row < M) {
            #pragma unroll
            for (int c = 0; c < CF; ++c) out[(size_t)row * 64 + c * 16 + rsel] = v[c] - m - ls;
        }
    }
}

extern "C" void kernel_launch(void* const* d_in, const int* in_sizes, int n_in,
                              void* d_out, int out_size, void* d_ws, size_t ws_size,
                              hipStream_t stream) {
    const float* x  = (const float*)d_in[0];
    const int* ei   = (const int*)d_in[1];
    const float* W0 = (const float*)d_in[2];
    const float* b0 = (const float*)d_in[3];
    const float* W1 = (const float*)d_in[4];
    const float* b1 = (const float*)d_in[5];
    const float* W2 = (const float*)d_in[6];
    const float* b2 = (const float*)d_in[7];
    const float* g1 = (const float*)d_in[8];
    const float* be1 = (const float*)d_in[9];
    const float* g2 = (const float*)d_in[10];
    const float* be2 = (const float*)d_in[11];

    const int N = in_sizes[0] / 128;
    const int E = in_sizes[1] / 2;
    const int* src = ei;
    const int* dst = ei + E;
    const int ntot = N + 1;
    const int nscan = (ntot + 1023) / 1024;

    size_t off = 0;
    auto carve = [&](size_t bytes) {
        void* p = (char*)d_ws + off;
        off += (bytes + 255) & ~(size_t)255;
        return p;
    };
    float* bufA   = (float*)carve((size_t)N * 128 * 4);
    float* bufB   = (float*)carve((size_t)N * 128 * 4);
    float* nA     = (float*)carve((size_t)N * 4);
    float* nB     = (float*)carve((size_t)N * 4);
    int* counts   = (int*)carve((size_t)(ntot + 64) * 4);  // +done counter
    int* done     = counts + ntot;
    int* offs     = (int*)carve((size_t)ntot * 4);
    int* partials = (int*)carve((size_t)256 * 4);
    int* csr      = (int*)carve((size_t)E * 4);
    unsigned short* w0p = (unsigned short*)carve((size_t)3 * 16384 * 2);
    unsigned short* w1p = (unsigned short*)carve((size_t)3 * 16384 * 2);
    unsigned short* w2p = (unsigned short*)carve((size_t)3 * 8192 * 2);

    const int gridN4 = (N + 3) / 4;
    const int gridE = (E + 255) / 256;
    const int nwaves = (N + 15) / 16;
    const int gridW = (nwaves + 3) / 4;

    // W planes (value-pinned, merged launches)
    wprep01_k<<<16, 256, 0, stream>>>(W0, W1, w0p, w1p);
    wprep2_k<<<4, 256, 0, stream>>>(W2, w2p);

    // CSR by destination (counts + done zeroed together)
    hipMemsetAsync(counts, 0, (size_t)(ntot + 64) * 4, stream);
    count_k<<<gridE, 256, 0, stream>>>(dst, E, counts);
    scan12_k<<<nscan, 256, 0, stream>>>(counts, partials, done, ntot, nscan);
    scan3_k<<<nscan, 256, 0, stream>>>(counts, partials, offs, ntot);
    scatter_k<<<gridE, 256, 0, stream>>>(src, dst, E, counts, csr);

    // ---- layer 0
    normpack_k<<<gridN4, 256, 0, stream>>>(x, bufA, nA, N);
    agg_k<<<gridN4, 256, 0, stream>>>(bufA, nA, offs, csr, bufB, N);
    mgemm_ln_k<<<gridW, 256, 0, stream>>>(bufB, w0p, b0, g1, be1, bufB, nB, nwaves, N);

    // ---- layer 1
    agg_k<<<gridN4, 256, 0, stream>>>(bufB, nB, offs, csr, bufA, N);
    mgemm_ln_k<<<gridW, 256, 0, stream>>>(bufA, w1p, b1, g2, be2, bufA, nA, nwaves, N);

    // ---- layer 2
    agg_k<<<gridN4, 256, 0, stream>>>(bufA, nA, offs, csr, bufB, N);
    mgemm_lsm_k<<<gridW, 256, 0, stream>>>(bufB, w2p, b2, (float*)d_out, nwaves, N);
}